// Round 16
// baseline (354.117 us; speedup 1.0000x reference)
//
#include <hip/hip_runtime.h>
#include <hip/hip_bf16.h>

typedef __bf16 bf16_t;
typedef __bf16 bf16x8 __attribute__((ext_vector_type(8)));
typedef float f32x4 __attribute__((ext_vector_type(4)));

typedef __attribute__((address_space(3))) void lds_void_t;
typedef const __attribute__((address_space(1))) void gbl_void_t;

static constexpr int S_LEN = 2048;
static constexpr int NBATCH = 2;
static constexpr int DM = 1024;
static constexpr int NH = 16;
static constexpr int HD = 64;
static constexpr int DFF = 4096;
static constexpr int MROWS = NBATCH * S_LEN;   // 4096
static constexpr int QKVN = 3072;              // merged q|k|v columns

// ---------------- RoPE cos/sin table: cs[0..S*64) = cos, cs[S*64..) = sin ---------
__global__ __launch_bounds__(256) void rope_table_k(float* __restrict__ cs) {
  int idx = blockIdx.x * 256 + threadIdx.x;     // 0 .. 2048*32-1
  int i = idx & 31, s = idx >> 5;
  float inv = powf(10000.0f, -(float)i / 32.0f);  // theta^{-2i/64}
  float ang = (float)s * inv;
  float c = cosf(ang), sn = sinf(ang);
  cs[s * 64 + i] = c;  cs[s * 64 + i + 32] = c;
  cs[S_LEN * 64 + s * 64 + i] = sn;  cs[S_LEN * 64 + s * 64 + i + 32] = sn;
}

// ---------------- GEMV: out[b][j] = act(vin[b] . W[:,j] + bias[j]) ------------------
__global__ __launch_bounds__(256) void gemv_k(const float* __restrict__ vin,
    const float* __restrict__ W, const float* __restrict__ bias,
    float* __restrict__ out, int N, int dosilu) {
  int b = blockIdx.y;
  int tj = threadIdx.x & 31, ti = threadIdx.x >> 5;
  int j = blockIdx.x * 32 + tj;
  const float* v = vin + b * DM;
  float acc = 0.f;
  int i0 = ti * 128;
#pragma unroll 8
  for (int i = i0; i < i0 + 128; ++i) acc += v[i] * W[(size_t)i * N + j];
  __shared__ float red[8][32];
  red[ti][tj] = acc;
  __syncthreads();
  if (threadIdx.x < 32) {
    float a = 0.f;
#pragma unroll
    for (int t = 0; t < 8; ++t) a += red[t][threadIdx.x];
    a += bias[j - tj + threadIdx.x];
    if (dosilu) a = a / (1.0f + expf(-a));
    out[(size_t)b * N + blockIdx.x * 32 + threadIdx.x] = a;
  }
}

// ---------------- ada-RMSNorm: out = x*rsqrt(mean x^2+eps)*w*(1+scale)+shift -------
template<typename T>
__global__ __launch_bounds__(256) void ada_rms_k(const T* __restrict__ x,
    const float* __restrict__ wnorm, const float* __restrict__ ss,
    bf16_t* __restrict__ out) {
  int row = blockIdx.x;                // 0..4095  (b = row/2048)
  int b = row >> 11;
  const T* xr = x + (size_t)row * DM;
  float xl[4]; float s = 0.f;
#pragma unroll
  for (int i = 0; i < 4; ++i) { xl[i] = (float)xr[threadIdx.x + i * 256]; s += xl[i] * xl[i]; }
#pragma unroll
  for (int d = 1; d < 64; d <<= 1) s += __shfl_xor(s, d);
  __shared__ float red[4];
  int w = threadIdx.x >> 6;
  if ((threadIdx.x & 63) == 0) red[w] = s;
  __syncthreads();
  s = red[0] + red[1] + red[2] + red[3];
  float r = rsqrtf(s * (1.0f / DM) + 1e-5f);
  bf16_t* orow = out + (size_t)row * DM;
#pragma unroll
  for (int i = 0; i < 4; ++i) {
    int j = threadIdx.x + i * 256;
    float sc = ss[b * 2048 + j], sh = ss[b * 2048 + 1024 + j];
    orow[j] = (bf16_t)(xl[i] * r * wnorm[j] * (1.0f + sc) + sh);
  }
}

// ---------------- merged weight prep: all transposes + bias concat, ONE launch -----
__global__ __launch_bounds__(256) void prep_k(
    const float* __restrict__ wq, const float* __restrict__ wk,
    const float* __restrict__ wv, const float* __restrict__ wo,
    const float* __restrict__ wg, const float* __restrict__ wu,
    const float* __restrict__ wd,
    bf16_t* __restrict__ wqkvT, bf16_t* __restrict__ woT,
    bf16_t* __restrict__ wguT, bf16_t* __restrict__ wdT,
    const float* __restrict__ bq, const float* __restrict__ bk,
    const float* __restrict__ bv, float* __restrict__ bcat) {
  int id = blockIdx.x;
  if (id >= 16384) {
    int i = (id - 16384) * 256 + threadIdx.x;
    if (i < 3072)
      bcat[i] = i < 1024 ? bq[i] : (i < 2048 ? bk[i - 1024] : bv[i - 2048]);
    return;
  }
  const float* in; bf16_t* outp; int K, N, ilv, t;
  if (id < 4096) {
    int j = id >> 10; t = id & 1023; K = 1024; N = 1024; ilv = 0;
    in   = j == 0 ? wq : j == 1 ? wk : j == 2 ? wv : wo;
    outp = j == 3 ? woT : wqkvT + (size_t)j * 1024 * 1024;
  } else if (id < 12288) {
    int j = (id - 4096) >> 12; t = (id - 4096) & 4095; K = 1024; N = 4096;
    ilv = 1 + j; in = j ? wu : wg; outp = wguT;
  } else {
    t = id - 12288; K = 4096; N = 1024; ilv = 0; in = wd; outp = wdT;
  }
  int nbx = N >> 5;
  int n0 = (t % nbx) * 32, k0 = (t / nbx) * 32;
  __shared__ float tl[32][33];
  int tx = threadIdx.x & 31, ty = threadIdx.x >> 5;
#pragma unroll
  for (int i = 0; i < 32; i += 8)
    tl[ty + i][tx] = in[(size_t)(k0 + ty + i) * N + n0 + tx];
  __syncthreads();
#pragma unroll
  for (int i = 0; i < 32; i += 8) {
    int n = n0 + ty + i;
    int row = (ilv == 0) ? n : ((n >> 4) * 32 + (n & 15) + (ilv == 2 ? 16 : 0));
    outp[(size_t)row * K + k0 + tx] = (bf16_t)tl[tx][ty + i];
  }
}

// ---------------- bf16 MFMA GEMM: C = A[M][K] @ BT[N][K]^T -------------------------
// BK=64: BM=256 x BN=128 tile, 8 waves (512 thr), SINGLE-buffered 48KB LDS,
//   launch_bounds(512,4) (the (512,6) VGPR cap of 85 spilled accumulators: R14).
// BK=128: BM=128 dbuf (128KB) for grid-limited GEMMs (1 block/CU), proven R10.
// Loop-carried stage pointers; both-sides chunk swizzle -> 0 bank conflicts (R9).
// EPI: 1 = +bias +residf(f32) -> bf16 out (WO + residual -> x2)
//      4 = +residb(bf16) -> f32 out       (down + residual -> d_out)
//      5 = QKV fused: +bias, q/k RoPE, q scaled 1/8; V -> vt[bh][d][s]
//      6 = fused FFN gate*up: interleaved BT; out = gelu(g)*u -> gb[4096][4096]
template<int EPI, int BK>
__global__ __launch_bounds__((BK == 64) ? 512 : 256, (BK == 64) ? 4 : 1) void gemm_bt(
    const bf16_t* __restrict__ A, const bf16_t* __restrict__ BT,
    int M, int N, int K,
    const float* __restrict__ bias, const float* __restrict__ residf,
    const bf16_t* __restrict__ residb, bf16_t* outb, float* outf,
    const float* __restrict__ cstab, bf16_t* __restrict__ vt) {
  constexpr int DB = (BK == 64) ? 1 : 2;
  constexpr int BM = (BK == 64) ? 256 : 128;
  const int col0 = blockIdx.x * 128, row0 = blockIdx.y * BM;
  const int tid = threadIdx.x, l = tid & 63, w = tid >> 6;   // w: 0..7 (BK64) / 0..3
  const int wr = (w >> 1) * 64, wc = (w & 1) * 64;
  const int lo = l & 15, hi = l >> 4;
  __shared__ __align__(16) bf16_t lA[DB][BM][BK];
  __shared__ __align__(16) bf16_t lB[DB][128][BK];
  f32x4 zero = {0.f, 0.f, 0.f, 0.f};
  f32x4 acc[4][4];
#pragma unroll
  for (int m = 0; m < 4; ++m)
#pragma unroll
    for (int n = 0; n < 4; ++n) acc[m][n] = zero;

  const int cmask = (BK == 64) ? (lo & 7) : lo;       // read-side swizzle key
  const int NT = K / BK;

  auto compute = [&](int buf) {
#pragma unroll
    for (int kk = 0; kk < BK; kk += 32) {
      bf16x8 af[4], bfr[4];
#pragma unroll
      for (int m = 0; m < 4; ++m)
        af[m] = *(const bf16x8*)&lA[buf][wr + m * 16 + lo][(((kk >> 3) + hi) ^ cmask) * 8];
#pragma unroll
      for (int n = 0; n < 4; ++n)
        bfr[n] = *(const bf16x8*)&lB[buf][wc + n * 16 + lo][(((kk >> 3) + hi) ^ cmask) * 8];
#pragma unroll
      for (int m = 0; m < 4; ++m)
#pragma unroll
        for (int n = 0; n < 4; ++n)
          acc[m][n] = __builtin_amdgcn_mfma_f32_16x16x32_bf16(af[m], bfr[n], acc[m][n], 0, 0, 0);
    }
  };

  if constexpr (DB == 1) {
    // BM=256: A = 4 issues/wave (rows w*32+i*8), B = 2 issues/wave (rows w*16+i*8)
    const int lrow = l >> 3;
    const int swzb = ((l & 7) ^ lrow) * 16;
    const char* pA[4]; const char* pB[2];
#pragma unroll
    for (int i = 0; i < 4; ++i)
      pA[i] = (const char*)&A[(size_t)(row0 + w * 32 + i * 8 + lrow) * K] + swzb;
#pragma unroll
    for (int i = 0; i < 2; ++i)
      pB[i] = (const char*)&BT[(size_t)(col0 + w * 16 + i * 8 + lrow) * K] + swzb;
    for (int t = 0; t < NT; ++t) {
      __syncthreads();               // prior compute done reading LDS
#pragma unroll
      for (int i = 0; i < 4; ++i) {
        __builtin_amdgcn_global_load_lds((gbl_void_t*)pA[i],
            (lds_void_t*)&lA[0][w * 32 + i * 8][0], 16, 0, 0);
        pA[i] += 128;                // BK=64 bf16 = 128 B
      }
#pragma unroll
      for (int i = 0; i < 2; ++i) {
        __builtin_amdgcn_global_load_lds((gbl_void_t*)pB[i],
            (lds_void_t*)&lB[0][w * 16 + i * 8][0], 16, 0, 0);
        pB[i] += 128;
      }
      __syncthreads();               // vmcnt(0) drain: tile landed
      compute(0);
    }
  } else {
    const int lrow = l >> 4;                        // 4 rows x 16 chunks per issue
    const char* pA[8]; const char* pB[8];
#pragma unroll
    for (int i = 0; i < 8; ++i) {
      int rbase = w * 32 + i * 4;
      int key = (i * 4 + lrow) & 15;
      int swzb = ((l & 15) ^ key) * 16;
      pA[i] = (const char*)&A[(size_t)(row0 + rbase + lrow) * K] + swzb;
      pB[i] = (const char*)&BT[(size_t)(col0 + rbase + lrow) * K] + swzb;
    }
    auto stage_p = [&](int buf) {
#pragma unroll
      for (int i = 0; i < 8; ++i) {
        int rbase = w * 32 + i * 4;
        __builtin_amdgcn_global_load_lds((gbl_void_t*)pA[i], (lds_void_t*)&lA[buf][rbase][0], 16, 0, 0);
        __builtin_amdgcn_global_load_lds((gbl_void_t*)pB[i], (lds_void_t*)&lB[buf][rbase][0], 16, 0, 0);
        pA[i] += 256; pB[i] += 256;  // BK=128 bf16 = 256 B
      }
    };
    stage_p(0);
    __syncthreads();                 // drains vmcnt(0): tile 0 landed
    int cur = 0;
    for (int t = 0; t < NT; ++t) {
      if (t + 1 < NT) stage_p(cur ^ 1);   // issue next BEFORE compute
      compute(cur);
      __syncthreads();
      cur ^= 1;
    }
  }

  if (EPI == 5) {
    if (col0 >= 2048) {
#pragma unroll
      for (int m = 0; m < 4; ++m) {
#pragma unroll
        for (int n = 0; n < 4; ++n) {
          int cl = col0 + wc + n * 16 + lo;
          int r0 = row0 + wr + m * 16 + hi * 4;      // j=0 row
          int dfull = cl - 2048;
          int bh = (r0 >> 11) * 16 + (dfull >> 6);
          int d = dfull & 63;
          float bb = bias[cl];
          __align__(8) bf16_t tmp[4];
#pragma unroll
          for (int j = 0; j < 4; ++j) tmp[j] = (bf16_t)(acc[m][n][j] + bb);
          *(uint2*)&vt[((size_t)bh * 64 + d) * S_LEN + (r0 & 2047)] = *(uint2*)tmp;
        }
      }
    } else {
#pragma unroll
      for (int m = 0; m < 4; ++m) {
#pragma unroll
        for (int n = 0; n < 2; ++n) {
          int cl = col0 + wc + n * 16 + lo;          // i = cl&63 < 32
          int i = cl & 63;
          float b1 = bias[cl], b2 = bias[cl + 32];
          float scale = (cl < 1024) ? 0.125f : 1.0f;
#pragma unroll
          for (int j = 0; j < 4; ++j) {
            int r = row0 + wr + m * 16 + hi * 4 + j;
            int s = r & 2047;
            float c = cstab[s * 64 + i], sn = cstab[S_LEN * 64 + s * 64 + i];
            float x1 = acc[m][n][j] + b1, x2 = acc[m][n + 2][j] + b2;
            size_t idx = (size_t)r * N + cl;
            outb[idx]      = (bf16_t)((x1 * c - x2 * sn) * scale);
            outb[idx + 32] = (bf16_t)((x2 * c + x1 * sn) * scale);
          }
        }
      }
    }
    return;
  }

  if (EPI == 6) {
    // even n = gate col j, odd n = up col j, j = (cl>>5)*16 + lo (same lane pair)
#pragma unroll
    for (int m = 0; m < 4; ++m) {
#pragma unroll
      for (int p = 0; p < 2; ++p) {
        int clg = col0 + wc + 2 * p * 16;
        int jcol = ((clg >> 5) << 4) + lo;
#pragma unroll
        for (int j = 0; j < 4; ++j) {
          int r = row0 + wr + m * 16 + hi * 4 + j;
          float g = acc[m][2 * p][j];
          float u = acc[m][2 * p + 1][j];
          g = 0.5f * g * (1.0f + erff(g * 0.70710678118f));
          outb[(size_t)r * DFF + jcol] = (bf16_t)(g * u);
        }
      }
    }
    return;
  }

#pragma unroll
  for (int m = 0; m < 4; ++m) {
#pragma unroll
    for (int n = 0; n < 4; ++n) {
#pragma unroll
      for (int j = 0; j < 4; ++j) {
        int r = row0 + wr + m * 16 + hi * 4 + j;      // C/D: row=(l>>4)*4+reg
        int cl = col0 + wc + n * 16 + lo;             //      col=l&15   (m89-verified)
        size_t idx = (size_t)r * N + cl;
        float vv = acc[m][n][j];
        if (EPI == 1)      { vv += bias[cl] + residf[idx]; outb[idx] = (bf16_t)vv; }
        else               { vv += (float)residb[idx]; outf[idx] = vv; }
      }
    }
  }
}

// ---------------- flash attention: kv-split waves ---------------------------------
// 8 waves: wave w owns q-rows (w&3)*32 (m=2 tiles) and kv-half (w>>2)*64 of each
// 128-kv tile. Halves the per-wave K/V fragment LDS reads (attn was LDS-BW-bound:
// ~350KB/tile/block). Independent online softmax per wave over its kv subset;
// one flash-combine merge at the end through LDS (reuses dead K/V region).
__global__ __launch_bounds__(512, 4) void attn_k(const bf16_t* __restrict__ qk,
    const bf16_t* __restrict__ vt, bf16_t* __restrict__ o) {
  int g = blockIdx.x;
  int orig = (g & 7) * 64 + (g >> 3);    // XCD swizzle: 64 consecutive per XCD
  int qblk = orig & 15;
  int bh = orig >> 4;
  int b = bh >> 4, h = bh & 15;
  const int q0 = qblk * 128;
  const int tid = threadIdx.x, l = tid & 63, w = tid >> 6;   // w in 0..7
  const int lo = l & 15, hi = l >> 4;
  const int wq = w & 3, koff = (w >> 2) * 64;
  const int rb = q0 + wq * 32;           // wave's first q-row

  __shared__ __align__(16) char smem[72704];
  bf16_t (*lk)[72]   = (bf16_t(*)[72])smem;              // [128][72]   18432 B
  bf16_t (*lvt)[136] = (bf16_t(*)[136])(smem + 18432);   // [64][136]   17408 B
  bf16_t (*lp)[72]   = (bf16_t(*)[72])(smem + 35840);    // [256][72]   36864 B (8w x 32r)
  float* obuf = (float*)smem;                            // merge: [4][32][64] 32768 B
  float* mlb  = (float*)(smem + 32768);                  // merge: [4][2][32]   1024 B

  bf16x8 qf[2][2];
#pragma unroll
  for (int m = 0; m < 2; ++m)
#pragma unroll
    for (int ks = 0; ks < 2; ++ks)
      qf[m][ks] = *(const bf16x8*)&qk[((size_t)(b * S_LEN) + rb + m * 16 + lo) * QKVN
                                      + h * HD + ks * 32 + hi * 8];

  f32x4 zero = {0.f, 0.f, 0.f, 0.f};
  f32x4 oa[2][4];
#pragma unroll
  for (int m = 0; m < 2; ++m)
#pragma unroll
    for (int n = 0; n < 4; ++n) oa[m][n] = zero;
  float mrow[2][4], lrow[2][4];
#pragma unroll
  for (int m = 0; m < 2; ++m)
#pragma unroll
    for (int j = 0; j < 4; ++j) { mrow[m][j] = -1e30f; lrow[m][j] = 0.f; }

  const size_t kbase = (size_t)(b * S_LEN) * QKVN + 1024 + h * HD;
  const size_t vbase = (size_t)bh * 64 * S_LEN;

  for (int t0 = 0; t0 < S_LEN; t0 += 128) {
    __syncthreads();
#pragma unroll
    for (int it = 0; it < 2; ++it) {
      int idx = it * 512 + tid;
      int r = idx >> 3, dc = (idx & 7) * 8;          // K: 128 rows x 64
      *(uint4*)&lk[r][dc] = *(const uint4*)&qk[kbase + (size_t)(t0 + r) * QKVN + dc];
      int d = idx >> 4, sc = (idx & 15) * 8;          // V^T: 64 rows x 128
      *(uint4*)&lvt[d][sc] = *(const uint4*)&vt[vbase + (size_t)d * S_LEN + t0 + sc];
    }
    __syncthreads();

    // S = Q(32x64) @ K^T(64x64-half): rows rb+m*16+(hi*4+j), cols koff+n*16+lo
    f32x4 s[2][4];
#pragma unroll
    for (int m = 0; m < 2; ++m)
#pragma unroll
      for (int n = 0; n < 4; ++n) s[m][n] = zero;
    __builtin_amdgcn_s_setprio(1);
#pragma unroll
    for (int ks = 0; ks < 2; ++ks) {
      bf16x8 bk[4];
#pragma unroll
      for (int n = 0; n < 4; ++n) bk[n] = *(const bf16x8*)&lk[koff + n * 16 + lo][ks * 32 + hi * 8];
#pragma unroll
      for (int m = 0; m < 2; ++m)
#pragma unroll
        for (int n = 0; n < 4; ++n)
          s[m][n] = __builtin_amdgcn_mfma_f32_16x16x32_bf16(qf[m][ks], bk[n], s[m][n], 0, 0, 0);
    }
    __builtin_amdgcn_s_setprio(0);

    // online softmax over this wave's 64 kv cols
#pragma unroll
    for (int m = 0; m < 2; ++m) {
#pragma unroll
      for (int j = 0; j < 4; ++j) {
        float mx = fmaxf(fmaxf(s[m][0][j], s[m][1][j]), fmaxf(s[m][2][j], s[m][3][j]));
        mx = fmaxf(mx, __shfl_xor(mx, 1));
        mx = fmaxf(mx, __shfl_xor(mx, 2));
        mx = fmaxf(mx, __shfl_xor(mx, 4));
        mx = fmaxf(mx, __shfl_xor(mx, 8));
        if (__any(mx > mrow[m][j] + 8.0f)) {
          float mn = fmaxf(mrow[m][j], mx);
          float corr = __expf(mrow[m][j] - mn);
          mrow[m][j] = mn;
          lrow[m][j] *= corr;
#pragma unroll
          for (int n = 0; n < 4; ++n) oa[m][n][j] *= corr;
        }
        float psum = 0.f;
#pragma unroll
        for (int n = 0; n < 4; ++n) {
          float p = __expf(s[m][n][j] - mrow[m][j]);
          psum += p;
          lp[w * 32 + m * 16 + hi * 4 + j][n * 16 + lo] = (bf16_t)p;
        }
        lrow[m][j] += psum;
      }
    }

    // O += P(32x64) @ V(64-half x 64)
    __builtin_amdgcn_s_setprio(1);
#pragma unroll
    for (int kk = 0; kk < 64; kk += 32) {
      bf16x8 ap[2], bv[4];
#pragma unroll
      for (int m = 0; m < 2; ++m) ap[m] = *(const bf16x8*)&lp[w * 32 + m * 16 + lo][kk + hi * 8];
#pragma unroll
      for (int n = 0; n < 4; ++n) bv[n] = *(const bf16x8*)&lvt[n * 16 + lo][koff + kk + hi * 8];
#pragma unroll
      for (int m = 0; m < 2; ++m)
#pragma unroll
        for (int n = 0; n < 4; ++n)
          oa[m][n] = __builtin_amdgcn_mfma_f32_16x16x32_bf16(ap[m], bv[n], oa[m][n], 0, 0, 0);
    }
    __builtin_amdgcn_s_setprio(0);
  }

  // row-sum lrow across the 16 lo lanes (each lane summed only its columns)
  float lsum[2][4];
#pragma unroll
  for (int m = 0; m < 2; ++m)
#pragma unroll
    for (int j = 0; j < 4; ++j) {
      float ls = lrow[m][j];
      ls += __shfl_xor(ls, 1); ls += __shfl_xor(ls, 2);
      ls += __shfl_xor(ls, 4); ls += __shfl_xor(ls, 8);
      lsum[m][j] = ls;
    }

  __syncthreads();            // everyone done with lk/lvt/lp
  if (w < 4) {
    // low wave: deposit partial O (f32), m, l into merge region
    float* ob = obuf + (size_t)wq * 32 * 64;
#pragma unroll
    for (int m = 0; m < 2; ++m)
#pragma unroll
      for (int j = 0; j < 4; ++j) {
        int r = m * 16 + hi * 4 + j;
#pragma unroll
        for (int n = 0; n < 4; ++n) ob[r * 64 + n * 16 + lo] = oa[m][n][j];
        mlb[wq * 64 + r] = mrow[m][j];        // [wq][0][r]
        mlb[wq * 64 + 32 + r] = lsum[m][j];   // [wq][1][r]
      }
  }
  __syncthreads();
  if (w >= 4) {
    // high wave: flash-combine with partner and write final output
    const float* ob = obuf + (size_t)wq * 32 * 64;
#pragma unroll
    for (int m = 0; m < 2; ++m)
#pragma unroll
      for (int j = 0; j < 4; ++j) {
        int r = m * 16 + hi * 4 + j;
        float m1 = mlb[wq * 64 + r], l1 = mlb[wq * 64 + 32 + r];
        float m2 = mrow[m][j], l2 = lsum[m][j];
        float mm = fmaxf(m1, m2);
        float e1 = __expf(m1 - mm), e2 = __expf(m2 - mm);
        float inv = 1.0f / (l1 * e1 + l2 * e2);
        int row = rb + r;
#pragma unroll
        for (int n = 0; n < 4; ++n) {
          float num = ob[r * 64 + n * 16 + lo] * e1 + oa[m][n][j] * e2;
          o[((size_t)(b * S_LEN) + row) * DM + h * HD + n * 16 + lo] = (bf16_t)(num * inv);
        }
      }
  }
}

// ---------------------------------------------------------------------------------
extern "C" void kernel_launch(void* const* d_in, const int* in_sizes, int n_in,
                              void* d_out, int out_size, void* d_ws, size_t ws_size,
                              hipStream_t stream) {
  const float* x    = (const float*)d_in[0];
  const float* te   = (const float*)d_in[1];
  const float* wn1  = (const float*)d_in[2];
  const float* t1w1 = (const float*)d_in[3];
  const float* t1b1 = (const float*)d_in[4];
  const float* t1w2 = (const float*)d_in[5];
  const float* t1b2 = (const float*)d_in[6];
  const float* wn2  = (const float*)d_in[7];
  const float* t2w1 = (const float*)d_in[8];
  const float* t2b1 = (const float*)d_in[9];
  const float* t2w2 = (const float*)d_in[10];
  const float* t2b2 = (const float*)d_in[11];
  const float* wq   = (const float*)d_in[12];
  const float* bq   = (const float*)d_in[13];
  const float* wk   = (const float*)d_in[14];
  const float* bk   = (const float*)d_in[15];
  const float* wv   = (const float*)d_in[16];
  const float* bv   = (const float*)d_in[17];
  const float* wo   = (const float*)d_in[18];
  const float* bo   = (const float*)d_in[19];
  const float* wg   = (const float*)d_in[20];
  const float* wu   = (const float*)d_in[21];
  const float* wd   = (const float*)d_in[22];
  float* out = (float*)d_out;

  char* ws = (char*)d_ws;
  const size_t MB = 1ull << 20;
  bf16_t* woT   = (bf16_t*)(ws + 0 * MB);    // 2 MB
  bf16_t* wguT  = (bf16_t*)(ws + 2 * MB);    // 16 MB (interleaved gate|up, 8192 x 1024)
  bf16_t* wdT   = (bf16_t*)(ws + 18 * MB);   // 8 MB
  bf16_t* nx    = (bf16_t*)(ws + 26 * MB);   // 8 MB
  bf16_t* wqkvT = (bf16_t*)(ws + 34 * MB);   // 6 MB
  bf16_t* qkvb  = (bf16_t*)(ws + 40 * MB);   // 24 MB (v-region unwritten)
  bf16_t* vt    = (bf16_t*)(ws + 64 * MB);   // 8 MB
  bf16_t* gb    = (bf16_t*)(ws + 40 * MB);   // 32 MB, aliases qkvb+vt (dead by FFN)
  bf16_t* attnb = (bf16_t*)(ws + 72 * MB);   // 8 MB
  bf16_t* x2b   = (bf16_t*)(ws + 80 * MB);   // 8 MB
  float*  cs    = (float*)(ws + 88 * MB);    // 1 MB
  float*  ss1   = (float*)(ws + 89 * MB);
  float*  ss2   = (float*)(ws + 89 * MB + 16384);
  float*  htmp  = (float*)(ws + 89 * MB + 32768);
  float*  bcat  = (float*)(ws + 89 * MB + 40960);

  rope_table_k<<<256, 256, 0, stream>>>(cs);
  gemv_k<<<dim3(32, 2), 256, 0, stream>>>(te, t1w1, t1b1, htmp, 1024, 1);
  gemv_k<<<dim3(64, 2), 256, 0, stream>>>(htmp, t1w2, t1b2, ss1, 2048, 0);
  gemv_k<<<dim3(32, 2), 256, 0, stream>>>(te, t2w1, t2b1, htmp, 1024, 1);
  gemv_k<<<dim3(64, 2), 256, 0, stream>>>(htmp, t2w2, t2b2, ss2, 2048, 0);

  // all weight transposes + bias concat in one launch
  prep_k<<<16396, 256, 0, stream>>>(wq, wk, wv, wo, wg, wu, wd,
                                    wqkvT, woT, wguT, wdT, bq, bk, bv, bcat);

  ada_rms_k<float><<<MROWS, 256, 0, stream>>>(x, wn1, ss1, nx);

  // merged QKV projection, 256x128 tiles (BM=256): fused bias+RoPE (q,k), V -> vt
  gemm_bt<5, 64><<<dim3(24, 16), 512, 0, stream>>>(nx, wqkvT, MROWS, QKVN, DM,
                                                   bcat, nullptr, nullptr, qkvb, nullptr, cs, vt);

  attn_k<<<512, 512, 0, stream>>>(qkvb, vt, attnb);

  // WO + bias + residual -> x2 (grid-limited: BK=128 dbuf, half the barriers)
  gemm_bt<1, 128><<<dim3(8, 32), 256, 0, stream>>>(attnb, woT, MROWS, DM, DM,
                                                   bo, x, nullptr, x2b, nullptr, nullptr, nullptr);

  ada_rms_k<bf16_t><<<MROWS, 256, 0, stream>>>(x2b, wn2, ss2, nx);

  // fused FFN, 256x128 tiles: gb = gelu(nx@wg) * (nx@wu)  (one GEMM, N=8192 ilv)
  gemm_bt<6, 64><<<dim3(64, 16), 512, 0, stream>>>(nx, wguT, MROWS, 2 * DFF, DM,
                                                   nullptr, nullptr, nullptr, gb, nullptr, nullptr, nullptr);
  // down + residual -> out (grid-limited: BK=128 dbuf)
  gemm_bt<4, 128><<<dim3(8, 32), 256, 0, stream>>>(gb, wdT, MROWS, DM, DFF,
                                                   nullptr, nullptr, x2b, nullptr, out, nullptr, nullptr);
}

// Round 17
// 321.699 us; speedup vs baseline: 1.1008x; 1.1008x over previous
//
#include <hip/hip_runtime.h>
#include <hip/hip_bf16.h>

typedef __bf16 bf16_t;
typedef __bf16 bf16x8 __attribute__((ext_vector_type(8)));
typedef float f32x4 __attribute__((ext_vector_type(4)));

typedef __attribute__((address_space(3))) void lds_void_t;
typedef const __attribute__((address_space(1))) void gbl_void_t;

static constexpr int S_LEN = 2048;
static constexpr int NBATCH = 2;
static constexpr int DM = 1024;
static constexpr int NH = 16;
static constexpr int HD = 64;
static constexpr int DFF = 4096;
static constexpr int MROWS = NBATCH * S_LEN;   // 4096
static constexpr int QKVN = 3072;              // merged q|k|v columns

// ---------------- RoPE cos/sin table: cs[0..S*64) = cos, cs[S*64..) = sin ---------
__global__ __launch_bounds__(256) void rope_table_k(float* __restrict__ cs) {
  int idx = blockIdx.x * 256 + threadIdx.x;     // 0 .. 2048*32-1
  int i = idx & 31, s = idx >> 5;
  float inv = powf(10000.0f, -(float)i / 32.0f);  // theta^{-2i/64}
  float ang = (float)s * inv;
  float c = cosf(ang), sn = sinf(ang);
  cs[s * 64 + i] = c;  cs[s * 64 + i + 32] = c;
  cs[S_LEN * 64 + s * 64 + i] = sn;  cs[S_LEN * 64 + s * 64 + i + 32] = sn;
}

// ---------------- GEMV: out[b][j] = act(vin[b] . W[:,j] + bias[j]) ------------------
__global__ __launch_bounds__(256) void gemv_k(const float* __restrict__ vin,
    const float* __restrict__ W, const float* __restrict__ bias,
    float* __restrict__ out, int N, int dosilu) {
  int b = blockIdx.y;
  int tj = threadIdx.x & 31, ti = threadIdx.x >> 5;
  int j = blockIdx.x * 32 + tj;
  const float* v = vin + b * DM;
  float acc = 0.f;
  int i0 = ti * 128;
#pragma unroll 8
  for (int i = i0; i < i0 + 128; ++i) acc += v[i] * W[(size_t)i * N + j];
  __shared__ float red[8][32];
  red[ti][tj] = acc;
  __syncthreads();
  if (threadIdx.x < 32) {
    float a = 0.f;
#pragma unroll
    for (int t = 0; t < 8; ++t) a += red[t][threadIdx.x];
    a += bias[j - tj + threadIdx.x];
    if (dosilu) a = a / (1.0f + expf(-a));
    out[(size_t)b * N + blockIdx.x * 32 + threadIdx.x] = a;
  }
}

// ---------------- ada-RMSNorm: out = x*rsqrt(mean x^2+eps)*w*(1+scale)+shift -------
template<typename T>
__global__ __launch_bounds__(256) void ada_rms_k(const T* __restrict__ x,
    const float* __restrict__ wnorm, const float* __restrict__ ss,
    bf16_t* __restrict__ out) {
  int row = blockIdx.x;                // 0..4095  (b = row/2048)
  int b = row >> 11;
  const T* xr = x + (size_t)row * DM;
  float xl[4]; float s = 0.f;
#pragma unroll
  for (int i = 0; i < 4; ++i) { xl[i] = (float)xr[threadIdx.x + i * 256]; s += xl[i] * xl[i]; }
#pragma unroll
  for (int d = 1; d < 64; d <<= 1) s += __shfl_xor(s, d);
  __shared__ float red[4];
  int w = threadIdx.x >> 6;
  if ((threadIdx.x & 63) == 0) red[w] = s;
  __syncthreads();
  s = red[0] + red[1] + red[2] + red[3];
  float r = rsqrtf(s * (1.0f / DM) + 1e-5f);
  bf16_t* orow = out + (size_t)row * DM;
#pragma unroll
  for (int i = 0; i < 4; ++i) {
    int j = threadIdx.x + i * 256;
    float sc = ss[b * 2048 + j], sh = ss[b * 2048 + 1024 + j];
    orow[j] = (bf16_t)(xl[i] * r * wnorm[j] * (1.0f + sc) + sh);
  }
}

// ---------------- merged weight prep: all transposes + bias concat, ONE launch -----
__global__ __launch_bounds__(256) void prep_k(
    const float* __restrict__ wq, const float* __restrict__ wk,
    const float* __restrict__ wv, const float* __restrict__ wo,
    const float* __restrict__ wg, const float* __restrict__ wu,
    const float* __restrict__ wd,
    bf16_t* __restrict__ wqkvT, bf16_t* __restrict__ woT,
    bf16_t* __restrict__ wguT, bf16_t* __restrict__ wdT,
    const float* __restrict__ bq, const float* __restrict__ bk,
    const float* __restrict__ bv, float* __restrict__ bcat) {
  int id = blockIdx.x;
  if (id >= 16384) {
    int i = (id - 16384) * 256 + threadIdx.x;
    if (i < 3072)
      bcat[i] = i < 1024 ? bq[i] : (i < 2048 ? bk[i - 1024] : bv[i - 2048]);
    return;
  }
  const float* in; bf16_t* outp; int K, N, ilv, t;
  if (id < 4096) {
    int j = id >> 10; t = id & 1023; K = 1024; N = 1024; ilv = 0;
    in   = j == 0 ? wq : j == 1 ? wk : j == 2 ? wv : wo;
    outp = j == 3 ? woT : wqkvT + (size_t)j * 1024 * 1024;
  } else if (id < 12288) {
    int j = (id - 4096) >> 12; t = (id - 4096) & 4095; K = 1024; N = 4096;
    ilv = 1 + j; in = j ? wu : wg; outp = wguT;
  } else {
    t = id - 12288; K = 4096; N = 1024; ilv = 0; in = wd; outp = wdT;
  }
  int nbx = N >> 5;
  int n0 = (t % nbx) * 32, k0 = (t / nbx) * 32;
  __shared__ float tl[32][33];
  int tx = threadIdx.x & 31, ty = threadIdx.x >> 5;
#pragma unroll
  for (int i = 0; i < 32; i += 8)
    tl[ty + i][tx] = in[(size_t)(k0 + ty + i) * N + n0 + tx];
  __syncthreads();
#pragma unroll
  for (int i = 0; i < 32; i += 8) {
    int n = n0 + ty + i;
    int row = (ilv == 0) ? n : ((n >> 4) * 32 + (n & 15) + (ilv == 2 ? 16 : 0));
    outp[(size_t)row * K + k0 + tx] = (bf16_t)tl[tx][ty + i];
  }
}

// ---------------- bf16 MFMA GEMM: C = A[M][K] @ BT[N][K]^T -------------------------
// BK=64: BM=256 x BN=128 tile, 8 waves (512 thr), SINGLE-buffered 48KB LDS,
//   launch_bounds(512,4) (the (512,6) VGPR cap of 85 spilled accumulators: R14).
// BK=128: BM=128 dbuf (128KB) for grid-limited GEMMs (1 block/CU), proven R10.
// Loop-carried stage pointers; both-sides chunk swizzle -> 0 bank conflicts (R9).
// EPI: 1 = +bias +residf(f32) -> bf16 out (WO + residual -> x2)
//      4 = +residb(bf16) -> f32 out       (down + residual -> d_out)
//      5 = QKV fused: +bias, q/k RoPE, q scaled 1/8; V -> vt[bh][d][s]
//      6 = fused FFN gate*up: interleaved BT; out = gelu(g)*u -> gb[4096][4096]
template<int EPI, int BK>
__global__ __launch_bounds__((BK == 64) ? 512 : 256, (BK == 64) ? 4 : 1) void gemm_bt(
    const bf16_t* __restrict__ A, const bf16_t* __restrict__ BT,
    int M, int N, int K,
    const float* __restrict__ bias, const float* __restrict__ residf,
    const bf16_t* __restrict__ residb, bf16_t* outb, float* outf,
    const float* __restrict__ cstab, bf16_t* __restrict__ vt) {
  constexpr int DB = (BK == 64) ? 1 : 2;
  constexpr int BM = (BK == 64) ? 256 : 128;
  const int col0 = blockIdx.x * 128, row0 = blockIdx.y * BM;
  const int tid = threadIdx.x, l = tid & 63, w = tid >> 6;   // w: 0..7 (BK64) / 0..3
  const int wr = (w >> 1) * 64, wc = (w & 1) * 64;
  const int lo = l & 15, hi = l >> 4;
  __shared__ __align__(16) bf16_t lA[DB][BM][BK];
  __shared__ __align__(16) bf16_t lB[DB][128][BK];
  f32x4 zero = {0.f, 0.f, 0.f, 0.f};
  f32x4 acc[4][4];
#pragma unroll
  for (int m = 0; m < 4; ++m)
#pragma unroll
    for (int n = 0; n < 4; ++n) acc[m][n] = zero;

  const int cmask = (BK == 64) ? (lo & 7) : lo;       // read-side swizzle key
  const int NT = K / BK;

  auto compute = [&](int buf) {
#pragma unroll
    for (int kk = 0; kk < BK; kk += 32) {
      bf16x8 af[4], bfr[4];
#pragma unroll
      for (int m = 0; m < 4; ++m)
        af[m] = *(const bf16x8*)&lA[buf][wr + m * 16 + lo][(((kk >> 3) + hi) ^ cmask) * 8];
#pragma unroll
      for (int n = 0; n < 4; ++n)
        bfr[n] = *(const bf16x8*)&lB[buf][wc + n * 16 + lo][(((kk >> 3) + hi) ^ cmask) * 8];
#pragma unroll
      for (int m = 0; m < 4; ++m)
#pragma unroll
        for (int n = 0; n < 4; ++n)
          acc[m][n] = __builtin_amdgcn_mfma_f32_16x16x32_bf16(af[m], bfr[n], acc[m][n], 0, 0, 0);
    }
  };

  if constexpr (DB == 1) {
    // BM=256: A = 4 issues/wave (rows w*32+i*8), B = 2 issues/wave (rows w*16+i*8)
    const int lrow = l >> 3;
    const int swzb = ((l & 7) ^ lrow) * 16;
    const char* pA[4]; const char* pB[2];
#pragma unroll
    for (int i = 0; i < 4; ++i)
      pA[i] = (const char*)&A[(size_t)(row0 + w * 32 + i * 8 + lrow) * K] + swzb;
#pragma unroll
    for (int i = 0; i < 2; ++i)
      pB[i] = (const char*)&BT[(size_t)(col0 + w * 16 + i * 8 + lrow) * K] + swzb;
    for (int t = 0; t < NT; ++t) {
      __syncthreads();               // prior compute done reading LDS
#pragma unroll
      for (int i = 0; i < 4; ++i) {
        __builtin_amdgcn_global_load_lds((gbl_void_t*)pA[i],
            (lds_void_t*)&lA[0][w * 32 + i * 8][0], 16, 0, 0);
        pA[i] += 128;                // BK=64 bf16 = 128 B
      }
#pragma unroll
      for (int i = 0; i < 2; ++i) {
        __builtin_amdgcn_global_load_lds((gbl_void_t*)pB[i],
            (lds_void_t*)&lB[0][w * 16 + i * 8][0], 16, 0, 0);
        pB[i] += 128;
      }
      __syncthreads();               // vmcnt(0) drain: tile landed
      compute(0);
    }
  } else {
    const int lrow = l >> 4;                        // 4 rows x 16 chunks per issue
    const char* pA[8]; const char* pB[8];
#pragma unroll
    for (int i = 0; i < 8; ++i) {
      int rbase = w * 32 + i * 4;
      int key = (i * 4 + lrow) & 15;
      int swzb = ((l & 15) ^ key) * 16;
      pA[i] = (const char*)&A[(size_t)(row0 + rbase + lrow) * K] + swzb;
      pB[i] = (const char*)&BT[(size_t)(col0 + rbase + lrow) * K] + swzb;
    }
    auto stage_p = [&](int buf) {
#pragma unroll
      for (int i = 0; i < 8; ++i) {
        int rbase = w * 32 + i * 4;
        __builtin_amdgcn_global_load_lds((gbl_void_t*)pA[i], (lds_void_t*)&lA[buf][rbase][0], 16, 0, 0);
        __builtin_amdgcn_global_load_lds((gbl_void_t*)pB[i], (lds_void_t*)&lB[buf][rbase][0], 16, 0, 0);
        pA[i] += 256; pB[i] += 256;  // BK=128 bf16 = 256 B
      }
    };
    stage_p(0);
    __syncthreads();                 // drains vmcnt(0): tile 0 landed
    int cur = 0;
    for (int t = 0; t < NT; ++t) {
      if (t + 1 < NT) stage_p(cur ^ 1);   // issue next BEFORE compute
      compute(cur);
      __syncthreads();
      cur ^= 1;
    }
  }

  if (EPI == 5) {
    if (col0 >= 2048) {
#pragma unroll
      for (int m = 0; m < 4; ++m) {
#pragma unroll
        for (int n = 0; n < 4; ++n) {
          int cl = col0 + wc + n * 16 + lo;
          int r0 = row0 + wr + m * 16 + hi * 4;      // j=0 row
          int dfull = cl - 2048;
          int bh = (r0 >> 11) * 16 + (dfull >> 6);
          int d = dfull & 63;
          float bb = bias[cl];
          __align__(8) bf16_t tmp[4];
#pragma unroll
          for (int j = 0; j < 4; ++j) tmp[j] = (bf16_t)(acc[m][n][j] + bb);
          *(uint2*)&vt[((size_t)bh * 64 + d) * S_LEN + (r0 & 2047)] = *(uint2*)tmp;
        }
      }
    } else {
#pragma unroll
      for (int m = 0; m < 4; ++m) {
#pragma unroll
        for (int n = 0; n < 2; ++n) {
          int cl = col0 + wc + n * 16 + lo;          // i = cl&63 < 32
          int i = cl & 63;
          float b1 = bias[cl], b2 = bias[cl + 32];
          float scale = (cl < 1024) ? 0.125f : 1.0f;
#pragma unroll
          for (int j = 0; j < 4; ++j) {
            int r = row0 + wr + m * 16 + hi * 4 + j;
            int s = r & 2047;
            float c = cstab[s * 64 + i], sn = cstab[S_LEN * 64 + s * 64 + i];
            float x1 = acc[m][n][j] + b1, x2 = acc[m][n + 2][j] + b2;
            size_t idx = (size_t)r * N + cl;
            outb[idx]      = (bf16_t)((x1 * c - x2 * sn) * scale);
            outb[idx + 32] = (bf16_t)((x2 * c + x1 * sn) * scale);
          }
        }
      }
    }
    return;
  }

  if (EPI == 6) {
    // even n = gate col j, odd n = up col j, j = (cl>>5)*16 + lo (same lane pair)
#pragma unroll
    for (int m = 0; m < 4; ++m) {
#pragma unroll
      for (int p = 0; p < 2; ++p) {
        int clg = col0 + wc + 2 * p * 16;
        int jcol = ((clg >> 5) << 4) + lo;
#pragma unroll
        for (int j = 0; j < 4; ++j) {
          int r = row0 + wr + m * 16 + hi * 4 + j;
          float g = acc[m][2 * p][j];
          float u = acc[m][2 * p + 1][j];
          g = 0.5f * g * (1.0f + erff(g * 0.70710678118f));
          outb[(size_t)r * DFF + jcol] = (bf16_t)(g * u);
        }
      }
    }
    return;
  }

#pragma unroll
  for (int m = 0; m < 4; ++m) {
#pragma unroll
    for (int n = 0; n < 4; ++n) {
#pragma unroll
      for (int j = 0; j < 4; ++j) {
        int r = row0 + wr + m * 16 + hi * 4 + j;      // C/D: row=(l>>4)*4+reg
        int cl = col0 + wc + n * 16 + lo;             //      col=l&15   (m89-verified)
        size_t idx = (size_t)r * N + cl;
        float vv = acc[m][n][j];
        if (EPI == 1)      { vv += bias[cl] + residf[idx]; outb[idx] = (bf16_t)vv; }
        else               { vv += (float)residb[idx]; outf[idx] = vv; }
      }
    }
  }
}

// ---------------- flash attention: 8 waves x 16 q-rows, KV tile = 128 --------------
// R7/R15-proven version (87.5us). R16's kv-split doubled live regs -> scratch
// spill (WRITE 10->38MB) -> reverted.
__global__ __launch_bounds__(512, 4) void attn_k(const bf16_t* __restrict__ qk,
    const bf16_t* __restrict__ vt, bf16_t* __restrict__ o) {
  int g = blockIdx.x;
  int orig = (g & 7) * 64 + (g >> 3);    // XCD swizzle: 64 consecutive per XCD
  int qblk = orig & 15;
  int bh = orig >> 4;
  int b = bh >> 4, h = bh & 15;
  const int q0 = qblk * 128;
  const int tid = threadIdx.x, l = tid & 63, w = tid >> 6;   // w in 0..7
  const int lo = l & 15, hi = l >> 4;

  __shared__ __align__(16) bf16_t lk[128][72];
  __shared__ __align__(16) bf16_t lvt[64][136];   // [d][kv]
  __shared__ __align__(16) bf16_t lp[8][16][136]; // per-wave P (16 rows x 128 kv)

  bf16x8 qf[2];
#pragma unroll
  for (int ks = 0; ks < 2; ++ks)
    qf[ks] = *(const bf16x8*)&qk[((size_t)(b * S_LEN) + q0 + w * 16 + lo) * QKVN
                                 + h * HD + ks * 32 + hi * 8];

  f32x4 zero = {0.f, 0.f, 0.f, 0.f};
  f32x4 oa[4];
#pragma unroll
  for (int n = 0; n < 4; ++n) oa[n] = zero;
  float mrow[4], lrow[4];
#pragma unroll
  for (int j = 0; j < 4; ++j) { mrow[j] = -1e30f; lrow[j] = 0.f; }

  const size_t kbase = (size_t)(b * S_LEN) * QKVN + 1024 + h * HD;
  const size_t vbase = (size_t)bh * 64 * S_LEN;

  for (int t0 = 0; t0 < S_LEN; t0 += 128) {
    __syncthreads();
#pragma unroll
    for (int it = 0; it < 2; ++it) {
      int idx = it * 512 + tid;
      int r = idx >> 3, dc = (idx & 7) * 8;          // K: 128 rows x 64
      *(uint4*)&lk[r][dc] = *(const uint4*)&qk[kbase + (size_t)(t0 + r) * QKVN + dc];
      int d = idx >> 4, sc = (idx & 15) * 8;          // V^T: 64 rows x 128
      *(uint4*)&lvt[d][sc] = *(const uint4*)&vt[vbase + (size_t)d * S_LEN + t0 + sc];
    }
    __syncthreads();

    f32x4 s[8];
#pragma unroll
    for (int n = 0; n < 8; ++n) s[n] = zero;
    __builtin_amdgcn_s_setprio(1);
#pragma unroll
    for (int ks = 0; ks < 2; ++ks) {
#pragma unroll
      for (int n = 0; n < 8; ++n) {
        bf16x8 bk = *(const bf16x8*)&lk[n * 16 + lo][ks * 32 + hi * 8];
        s[n] = __builtin_amdgcn_mfma_f32_16x16x32_bf16(qf[ks], bk, s[n], 0, 0, 0);
      }
    }
    __builtin_amdgcn_s_setprio(0);

#pragma unroll
    for (int j = 0; j < 4; ++j) {
      float mx = fmaxf(fmaxf(fmaxf(s[0][j], s[1][j]), fmaxf(s[2][j], s[3][j])),
                       fmaxf(fmaxf(s[4][j], s[5][j]), fmaxf(s[6][j], s[7][j])));
      mx = fmaxf(mx, __shfl_xor(mx, 1));
      mx = fmaxf(mx, __shfl_xor(mx, 2));
      mx = fmaxf(mx, __shfl_xor(mx, 4));
      mx = fmaxf(mx, __shfl_xor(mx, 8));
      if (__any(mx > mrow[j] + 8.0f)) {
        float mn = fmaxf(mrow[j], mx);
        float corr = __expf(mrow[j] - mn);
        mrow[j] = mn;
        lrow[j] *= corr;
#pragma unroll
        for (int n = 0; n < 4; ++n) oa[n][j] *= corr;
      }
      float psum = 0.f;
#pragma unroll
      for (int n = 0; n < 8; ++n) {
        float p = __expf(s[n][j] - mrow[j]);
        psum += p;
        lp[w][hi * 4 + j][n * 16 + lo] = (bf16_t)p;
      }
      lrow[j] += psum;
    }

    __builtin_amdgcn_s_setprio(1);
#pragma unroll
    for (int kk = 0; kk < 128; kk += 32) {
      bf16x8 ap = *(const bf16x8*)&lp[w][lo][kk + hi * 8];
#pragma unroll
      for (int n = 0; n < 4; ++n) {
        bf16x8 bv = *(const bf16x8*)&lvt[n * 16 + lo][kk + hi * 8];
        oa[n] = __builtin_amdgcn_mfma_f32_16x16x32_bf16(ap, bv, oa[n], 0, 0, 0);
      }
    }
    __builtin_amdgcn_s_setprio(0);
  }

#pragma unroll
  for (int j = 0; j < 4; ++j) {
    float ls = lrow[j];
    ls += __shfl_xor(ls, 1); ls += __shfl_xor(ls, 2);
    ls += __shfl_xor(ls, 4); ls += __shfl_xor(ls, 8);
    float inv = 1.0f / ls;
    int row = q0 + w * 16 + hi * 4 + j;
#pragma unroll
    for (int n = 0; n < 4; ++n)
      o[((size_t)(b * S_LEN) + row) * DM + h * HD + n * 16 + lo] = (bf16_t)(oa[n][j] * inv);
  }
}

// ---------------------------------------------------------------------------------
extern "C" void kernel_launch(void* const* d_in, const int* in_sizes, int n_in,
                              void* d_out, int out_size, void* d_ws, size_t ws_size,
                              hipStream_t stream) {
  const float* x    = (const float*)d_in[0];
  const float* te   = (const float*)d_in[1];
  const float* wn1  = (const float*)d_in[2];
  const float* t1w1 = (const float*)d_in[3];
  const float* t1b1 = (const float*)d_in[4];
  const float* t1w2 = (const float*)d_in[5];
  const float* t1b2 = (const float*)d_in[6];
  const float* wn2  = (const float*)d_in[7];
  const float* t2w1 = (const float*)d_in[8];
  const float* t2b1 = (const float*)d_in[9];
  const float* t2w2 = (const float*)d_in[10];
  const float* t2b2 = (const float*)d_in[11];
  const float* wq   = (const float*)d_in[12];
  const float* bq   = (const float*)d_in[13];
  const float* wk   = (const float*)d_in[14];
  const float* bk   = (const float*)d_in[15];
  const float* wv   = (const float*)d_in[16];
  const float* bv   = (const float*)d_in[17];
  const float* wo   = (const float*)d_in[18];
  const float* bo   = (const float*)d_in[19];
  const float* wg   = (const float*)d_in[20];
  const float* wu   = (const float*)d_in[21];
  const float* wd   = (const float*)d_in[22];
  float* out = (float*)d_out;

  char* ws = (char*)d_ws;
  const size_t MB = 1ull << 20;
  bf16_t* woT   = (bf16_t*)(ws + 0 * MB);    // 2 MB
  bf16_t* wguT  = (bf16_t*)(ws + 2 * MB);    // 16 MB (interleaved gate|up, 8192 x 1024)
  bf16_t* wdT   = (bf16_t*)(ws + 18 * MB);   // 8 MB
  bf16_t* nx    = (bf16_t*)(ws + 26 * MB);   // 8 MB
  bf16_t* wqkvT = (bf16_t*)(ws + 34 * MB);   // 6 MB
  bf16_t* qkvb  = (bf16_t*)(ws + 40 * MB);   // 24 MB (v-region unwritten)
  bf16_t* vt    = (bf16_t*)(ws + 64 * MB);   // 8 MB
  bf16_t* gb    = (bf16_t*)(ws + 40 * MB);   // 32 MB, aliases qkvb+vt (dead by FFN)
  bf16_t* attnb = (bf16_t*)(ws + 72 * MB);   // 8 MB
  bf16_t* x2b   = (bf16_t*)(ws + 80 * MB);   // 8 MB
  float*  cs    = (float*)(ws + 88 * MB);    // 1 MB
  float*  ss1   = (float*)(ws + 89 * MB);
  float*  ss2   = (float*)(ws + 89 * MB + 16384);
  float*  htmp  = (float*)(ws + 89 * MB + 32768);
  float*  bcat  = (float*)(ws + 89 * MB + 40960);

  rope_table_k<<<256, 256, 0, stream>>>(cs);
  gemv_k<<<dim3(32, 2), 256, 0, stream>>>(te, t1w1, t1b1, htmp, 1024, 1);
  gemv_k<<<dim3(64, 2), 256, 0, stream>>>(htmp, t1w2, t1b2, ss1, 2048, 0);
  gemv_k<<<dim3(32, 2), 256, 0, stream>>>(te, t2w1, t2b1, htmp, 1024, 1);
  gemv_k<<<dim3(64, 2), 256, 0, stream>>>(htmp, t2w2, t2b2, ss2, 2048, 0);

  // all weight transposes + bias concat in one launch
  prep_k<<<16396, 256, 0, stream>>>(wq, wk, wv, wo, wg, wu, wd,
                                    wqkvT, woT, wguT, wdT, bq, bk, bv, bcat);

  ada_rms_k<float><<<MROWS, 256, 0, stream>>>(x, wn1, ss1, nx);

  // merged QKV projection, 256x128 tiles (BM=256): fused bias+RoPE (q,k), V -> vt
  gemm_bt<5, 64><<<dim3(24, 16), 512, 0, stream>>>(nx, wqkvT, MROWS, QKVN, DM,
                                                   bcat, nullptr, nullptr, qkvb, nullptr, cs, vt);

  attn_k<<<512, 512, 0, stream>>>(qkvb, vt, attnb);

  // WO + bias + residual -> x2 (grid-limited: BK=128 dbuf, half the barriers)
  gemm_bt<1, 128><<<dim3(8, 32), 256, 0, stream>>>(attnb, woT, MROWS, DM, DM,
                                                   bo, x, nullptr, x2b, nullptr, nullptr, nullptr);

  ada_rms_k<bf16_t><<<MROWS, 256, 0, stream>>>(x2b, wn2, ss2, nx);

  // fused FFN, 256x128 tiles: gb = gelu(nx@wg) * (nx@wu)  (one GEMM, N=8192 ilv)
  gemm_bt<6, 64><<<dim3(64, 16), 512, 0, stream>>>(nx, wguT, MROWS, 2 * DFF, DM,
                                                   nullptr, nullptr, nullptr, gb, nullptr, nullptr, nullptr);
  // down + residual -> out (grid-limited: BK=128 dbuf)
  gemm_bt<4, 128><<<dim3(8, 32), 256, 0, stream>>>(gb, wdT, MROWS, DM, DFF,
                                                   nullptr, nullptr, x2b, nullptr, out, nullptr, nullptr);
}

// Round 18
// 317.461 us; speedup vs baseline: 1.1155x; 1.0133x over previous
//
#include <hip/hip_runtime.h>
#include <hip/hip_bf16.h>

typedef __bf16 bf16_t;
typedef __bf16 bf16x8 __attribute__((ext_vector_type(8)));
typedef float f32x4 __attribute__((ext_vector_type(4)));

typedef __attribute__((address_space(3))) void lds_void_t;
typedef const __attribute__((address_space(1))) void gbl_void_t;

static constexpr int S_LEN = 2048;
static constexpr int NBATCH = 2;
static constexpr int DM = 1024;
static constexpr int NH = 16;
static constexpr int HD = 64;
static constexpr int DFF = 4096;
static constexpr int MROWS = NBATCH * S_LEN;   // 4096
static constexpr int QKVN = 3072;              // merged q|k|v columns

// ---------------- GEMV: out[b][j] = act(vin[b] . W[:,j] + bias[j]) ------------------
__global__ __launch_bounds__(256) void gemv_k(const float* __restrict__ vin,
    const float* __restrict__ W, const float* __restrict__ bias,
    float* __restrict__ out, int N, int dosilu) {
  int b = blockIdx.y;
  int tj = threadIdx.x & 31, ti = threadIdx.x >> 5;
  int j = blockIdx.x * 32 + tj;
  const float* v = vin + b * DM;
  float acc = 0.f;
  int i0 = ti * 128;
#pragma unroll 8
  for (int i = i0; i < i0 + 128; ++i) acc += v[i] * W[(size_t)i * N + j];
  __shared__ float red[8][32];
  red[ti][tj] = acc;
  __syncthreads();
  if (threadIdx.x < 32) {
    float a = 0.f;
#pragma unroll
    for (int t = 0; t < 8; ++t) a += red[t][threadIdx.x];
    a += bias[j - tj + threadIdx.x];
    if (dosilu) a = a / (1.0f + expf(-a));
    out[(size_t)b * N + blockIdx.x * 32 + threadIdx.x] = a;
  }
}

// ---------------- ada-RMSNorm: out = x*rsqrt(mean x^2+eps)*w*(1+scale)+shift -------
template<typename T>
__global__ __launch_bounds__(256) void ada_rms_k(const T* __restrict__ x,
    const float* __restrict__ wnorm, const float* __restrict__ ss,
    bf16_t* __restrict__ out) {
  int row = blockIdx.x;                // 0..4095  (b = row/2048)
  int b = row >> 11;
  const T* xr = x + (size_t)row * DM;
  float xl[4]; float s = 0.f;
#pragma unroll
  for (int i = 0; i < 4; ++i) { xl[i] = (float)xr[threadIdx.x + i * 256]; s += xl[i] * xl[i]; }
#pragma unroll
  for (int d = 1; d < 64; d <<= 1) s += __shfl_xor(s, d);
  __shared__ float red[4];
  int w = threadIdx.x >> 6;
  if ((threadIdx.x & 63) == 0) red[w] = s;
  __syncthreads();
  s = red[0] + red[1] + red[2] + red[3];
  float r = rsqrtf(s * (1.0f / DM) + 1e-5f);
  bf16_t* orow = out + (size_t)row * DM;
#pragma unroll
  for (int i = 0; i < 4; ++i) {
    int j = threadIdx.x + i * 256;
    float sc = ss[b * 2048 + j], sh = ss[b * 2048 + 1024 + j];
    orow[j] = (bf16_t)(xl[i] * r * wnorm[j] * (1.0f + sc) + sh);
  }
}

// ---------------- merged prep: transposes (64x32 tiles, uint4 stores) + bias concat
//                  + RoPE table, ONE launch ---------------------------------------
// id layout: [0,2048)  wq/wk/wv/wo  (512 blocks each: 16 k-tiles x 32 n-tiles)
//            [2048,6144)  wg (ilv=1) then wu (ilv=2), 2048 each
//            [6144,8192)  wd
//            [8192,8204)  bias concat
//            [8204,8460)  rope cos/sin table
__global__ __launch_bounds__(256) void prep_k(
    const float* __restrict__ wq, const float* __restrict__ wk,
    const float* __restrict__ wv, const float* __restrict__ wo,
    const float* __restrict__ wg, const float* __restrict__ wu,
    const float* __restrict__ wd,
    bf16_t* __restrict__ wqkvT, bf16_t* __restrict__ woT,
    bf16_t* __restrict__ wguT, bf16_t* __restrict__ wdT,
    const float* __restrict__ bq, const float* __restrict__ bk,
    const float* __restrict__ bv, float* __restrict__ bcat,
    float* __restrict__ cs) {
  int id = blockIdx.x;
  if (id >= 8204) {
    int idx = (id - 8204) * 256 + threadIdx.x;    // 0..65535
    int i = idx & 31, s = idx >> 5;
    float inv = powf(10000.0f, -(float)i / 32.0f);
    float ang = (float)s * inv;
    float c = cosf(ang), sn = sinf(ang);
    cs[s * 64 + i] = c;  cs[s * 64 + i + 32] = c;
    cs[S_LEN * 64 + s * 64 + i] = sn;  cs[S_LEN * 64 + s * 64 + i + 32] = sn;
    return;
  }
  if (id >= 8192) {
    int i = (id - 8192) * 256 + threadIdx.x;
    if (i < 3072)
      bcat[i] = i < 1024 ? bq[i] : (i < 2048 ? bk[i - 1024] : bv[i - 2048]);
    return;
  }
  const float* in; bf16_t* outp; int K, N, ilv, t;
  if (id < 2048) {
    int j = id >> 9; t = id & 511; K = 1024; N = 1024; ilv = 0;
    in   = j == 0 ? wq : j == 1 ? wk : j == 2 ? wv : wo;
    outp = j == 3 ? woT : wqkvT + (size_t)j * 1024 * 1024;
  } else if (id < 6144) {
    int j = (id - 2048) >> 11; t = (id - 2048) & 2047; K = 1024; N = 4096;
    ilv = 1 + j; in = j ? wu : wg; outp = wguT;
  } else {
    t = id - 6144; K = 4096; N = 1024; ilv = 0; in = wd; outp = wdT;
  }
  int nbx = N >> 5;
  int n0 = (t % nbx) * 32, k0 = (t / nbx) * 64;
  __shared__ float tl[64][33];
  int tx = threadIdx.x & 31, ty = threadIdx.x >> 5;
#pragma unroll
  for (int i = 0; i < 64; i += 8)
    tl[ty + i][tx] = in[(size_t)(k0 + ty + i) * N + n0 + tx];
  __syncthreads();
  {
    int jn = threadIdx.x >> 3, kc = (threadIdx.x & 7) * 8;
    int n = n0 + jn;
    int row = (ilv == 0) ? n : ((n >> 4) * 32 + (n & 15) + (ilv == 2 ? 16 : 0));
    __align__(16) bf16_t v[8];
#pragma unroll
    for (int j = 0; j < 8; ++j) v[j] = (bf16_t)tl[kc + j][jn];
    *(uint4*)&outp[(size_t)row * K + k0 + kc] = *(uint4*)v;
  }
}

// ---------------- bf16 MFMA GEMM: C = A[M][K] @ BT[N][K]^T -------------------------
// BK=64: BM=256 x BN=128 tile, 8 waves (512 thr), SINGLE-buffered 48KB LDS,
//   launch_bounds(512,4) (the (512,6) VGPR cap of 85 spilled accumulators: R14).
// BK=128: BM=128 dbuf (128KB) for grid-limited GEMMs (1 block/CU), proven R10.
// Loop-carried stage pointers; both-sides chunk swizzle -> 0 bank conflicts (R9).
// EPI: 1 = +bias +residf(f32) -> bf16 out (WO + residual -> x2)
//      4 = +residb(bf16) -> f32 out       (down + residual -> d_out)
//      5 = QKV fused: +bias, q/k RoPE, q scaled 1/8; V -> vt[bh][d][s]
//      6 = fused FFN gate*up: interleaved BT; out = gelu(g)*u -> gb[4096][4096]
template<int EPI, int BK>
__global__ __launch_bounds__((BK == 64) ? 512 : 256, (BK == 64) ? 4 : 1) void gemm_bt(
    const bf16_t* __restrict__ A, const bf16_t* __restrict__ BT,
    int M, int N, int K,
    const float* __restrict__ bias, const float* __restrict__ residf,
    const bf16_t* __restrict__ residb, bf16_t* outb, float* outf,
    const float* __restrict__ cstab, bf16_t* __restrict__ vt) {
  constexpr int DB = (BK == 64) ? 1 : 2;
  constexpr int BM = (BK == 64) ? 256 : 128;
  const int col0 = blockIdx.x * 128, row0 = blockIdx.y * BM;
  const int tid = threadIdx.x, l = tid & 63, w = tid >> 6;   // w: 0..7 (BK64) / 0..3
  const int wr = (w >> 1) * 64, wc = (w & 1) * 64;
  const int lo = l & 15, hi = l >> 4;
  __shared__ __align__(16) bf16_t lA[DB][BM][BK];
  __shared__ __align__(16) bf16_t lB[DB][128][BK];
  f32x4 zero = {0.f, 0.f, 0.f, 0.f};
  f32x4 acc[4][4];
#pragma unroll
  for (int m = 0; m < 4; ++m)
#pragma unroll
    for (int n = 0; n < 4; ++n) acc[m][n] = zero;

  const int cmask = (BK == 64) ? (lo & 7) : lo;       // read-side swizzle key
  const int NT = K / BK;

  auto compute = [&](int buf) {
#pragma unroll
    for (int kk = 0; kk < BK; kk += 32) {
      bf16x8 af[4], bfr[4];
#pragma unroll
      for (int m = 0; m < 4; ++m)
        af[m] = *(const bf16x8*)&lA[buf][wr + m * 16 + lo][(((kk >> 3) + hi) ^ cmask) * 8];
#pragma unroll
      for (int n = 0; n < 4; ++n)
        bfr[n] = *(const bf16x8*)&lB[buf][wc + n * 16 + lo][(((kk >> 3) + hi) ^ cmask) * 8];
#pragma unroll
      for (int m = 0; m < 4; ++m)
#pragma unroll
        for (int n = 0; n < 4; ++n)
          acc[m][n] = __builtin_amdgcn_mfma_f32_16x16x32_bf16(af[m], bfr[n], acc[m][n], 0, 0, 0);
    }
  };

  if constexpr (DB == 1) {
    // BM=256: A = 4 issues/wave (rows w*32+i*8), B = 2 issues/wave (rows w*16+i*8)
    const int lrow = l >> 3;
    const int swzb = ((l & 7) ^ lrow) * 16;
    const char* pA[4]; const char* pB[2];
#pragma unroll
    for (int i = 0; i < 4; ++i)
      pA[i] = (const char*)&A[(size_t)(row0 + w * 32 + i * 8 + lrow) * K] + swzb;
#pragma unroll
    for (int i = 0; i < 2; ++i)
      pB[i] = (const char*)&BT[(size_t)(col0 + w * 16 + i * 8 + lrow) * K] + swzb;
    for (int t = 0; t < NT; ++t) {
      __syncthreads();               // prior compute done reading LDS
#pragma unroll
      for (int i = 0; i < 4; ++i) {
        __builtin_amdgcn_global_load_lds((gbl_void_t*)pA[i],
            (lds_void_t*)&lA[0][w * 32 + i * 8][0], 16, 0, 0);
        pA[i] += 128;                // BK=64 bf16 = 128 B
      }
#pragma unroll
      for (int i = 0; i < 2; ++i) {
        __builtin_amdgcn_global_load_lds((gbl_void_t*)pB[i],
            (lds_void_t*)&lB[0][w * 16 + i * 8][0], 16, 0, 0);
        pB[i] += 128;
      }
      __syncthreads();               // vmcnt(0) drain: tile landed
      compute(0);
    }
  } else {
    const int lrow = l >> 4;                        // 4 rows x 16 chunks per issue
    const char* pA[8]; const char* pB[8];
#pragma unroll
    for (int i = 0; i < 8; ++i) {
      int rbase = w * 32 + i * 4;
      int key = (i * 4 + lrow) & 15;
      int swzb = ((l & 15) ^ key) * 16;
      pA[i] = (const char*)&A[(size_t)(row0 + rbase + lrow) * K] + swzb;
      pB[i] = (const char*)&BT[(size_t)(col0 + rbase + lrow) * K] + swzb;
    }
    auto stage_p = [&](int buf) {
#pragma unroll
      for (int i = 0; i < 8; ++i) {
        int rbase = w * 32 + i * 4;
        __builtin_amdgcn_global_load_lds((gbl_void_t*)pA[i], (lds_void_t*)&lA[buf][rbase][0], 16, 0, 0);
        __builtin_amdgcn_global_load_lds((gbl_void_t*)pB[i], (lds_void_t*)&lB[buf][rbase][0], 16, 0, 0);
        pA[i] += 256; pB[i] += 256;  // BK=128 bf16 = 256 B
      }
    };
    stage_p(0);
    __syncthreads();                 // drains vmcnt(0): tile 0 landed
    int cur = 0;
    for (int t = 0; t < NT; ++t) {
      if (t + 1 < NT) stage_p(cur ^ 1);   // issue next BEFORE compute
      compute(cur);
      __syncthreads();
      cur ^= 1;
    }
  }

  if (EPI == 5) {
    if (col0 >= 2048) {
#pragma unroll
      for (int m = 0; m < 4; ++m) {
#pragma unroll
        for (int n = 0; n < 4; ++n) {
          int cl = col0 + wc + n * 16 + lo;
          int r0 = row0 + wr + m * 16 + hi * 4;      // j=0 row
          int dfull = cl - 2048;
          int bh = (r0 >> 11) * 16 + (dfull >> 6);
          int d = dfull & 63;
          float bb = bias[cl];
          __align__(8) bf16_t tmp[4];
#pragma unroll
          for (int j = 0; j < 4; ++j) tmp[j] = (bf16_t)(acc[m][n][j] + bb);
          *(uint2*)&vt[((size_t)bh * 64 + d) * S_LEN + (r0 & 2047)] = *(uint2*)tmp;
        }
      }
    } else {
#pragma unroll
      for (int m = 0; m < 4; ++m) {
#pragma unroll
        for (int n = 0; n < 2; ++n) {
          int cl = col0 + wc + n * 16 + lo;          // i = cl&63 < 32
          int i = cl & 63;
          float b1 = bias[cl], b2 = bias[cl + 32];
          float scale = (cl < 1024) ? 0.125f : 1.0f;
#pragma unroll
          for (int j = 0; j < 4; ++j) {
            int r = row0 + wr + m * 16 + hi * 4 + j;
            int s = r & 2047;
            float c = cstab[s * 64 + i], sn = cstab[S_LEN * 64 + s * 64 + i];
            float x1 = acc[m][n][j] + b1, x2 = acc[m][n + 2][j] + b2;
            size_t idx = (size_t)r * N + cl;
            outb[idx]      = (bf16_t)((x1 * c - x2 * sn) * scale);
            outb[idx + 32] = (bf16_t)((x2 * c + x1 * sn) * scale);
          }
        }
      }
    }
    return;
  }

  if (EPI == 6) {
    // even n = gate col j, odd n = up col j, j = (cl>>5)*16 + lo (same lane pair)
#pragma unroll
    for (int m = 0; m < 4; ++m) {
#pragma unroll
      for (int p = 0; p < 2; ++p) {
        int clg = col0 + wc + 2 * p * 16;
        int jcol = ((clg >> 5) << 4) + lo;
#pragma unroll
        for (int j = 0; j < 4; ++j) {
          int r = row0 + wr + m * 16 + hi * 4 + j;
          float g = acc[m][2 * p][j];
          float u = acc[m][2 * p + 1][j];
          g = 0.5f * g * (1.0f + erff(g * 0.70710678118f));
          outb[(size_t)r * DFF + jcol] = (bf16_t)(g * u);
        }
      }
    }
    return;
  }

#pragma unroll
  for (int m = 0; m < 4; ++m) {
#pragma unroll
    for (int n = 0; n < 4; ++n) {
#pragma unroll
      for (int j = 0; j < 4; ++j) {
        int r = row0 + wr + m * 16 + hi * 4 + j;      // C/D: row=(l>>4)*4+reg
        int cl = col0 + wc + n * 16 + lo;             //      col=l&15   (m89-verified)
        size_t idx = (size_t)r * N + cl;
        float vv = acc[m][n][j];
        if (EPI == 1)      { vv += bias[cl] + residf[idx]; outb[idx] = (bf16_t)vv; }
        else               { vv += (float)residb[idx]; outf[idx] = vv; }
      }
    }
  }
}

// ---------------- flash attention: 8 waves x 16 q-rows, KV tile = 128 --------------
// R7/R15-proven structure (87.5us); lp stride 136->132 (264B rows ≡ 2 banks mod 32:
// P-store hi-rows land on 4 distinct bank octets -> 4-way -> 2-way conflicts).
__global__ __launch_bounds__(512, 4) void attn_k(const bf16_t* __restrict__ qk,
    const bf16_t* __restrict__ vt, bf16_t* __restrict__ o) {
  int g = blockIdx.x;
  int orig = (g & 7) * 64 + (g >> 3);    // XCD swizzle: 64 consecutive per XCD
  int qblk = orig & 15;
  int bh = orig >> 4;
  int b = bh >> 4, h = bh & 15;
  const int q0 = qblk * 128;
  const int tid = threadIdx.x, l = tid & 63, w = tid >> 6;   // w in 0..7
  const int lo = l & 15, hi = l >> 4;

  __shared__ __align__(16) bf16_t lk[128][72];
  __shared__ __align__(16) bf16_t lvt[64][136];   // [d][kv]
  __shared__ __align__(16) bf16_t lp[8][16][132]; // per-wave P (16 rows x 128 kv)

  bf16x8 qf[2];
#pragma unroll
  for (int ks = 0; ks < 2; ++ks)
    qf[ks] = *(const bf16x8*)&qk[((size_t)(b * S_LEN) + q0 + w * 16 + lo) * QKVN
                                 + h * HD + ks * 32 + hi * 8];

  f32x4 zero = {0.f, 0.f, 0.f, 0.f};
  f32x4 oa[4];
#pragma unroll
  for (int n = 0; n < 4; ++n) oa[n] = zero;
  float mrow[4], lrow[4];
#pragma unroll
  for (int j = 0; j < 4; ++j) { mrow[j] = -1e30f; lrow[j] = 0.f; }

  const size_t kbase = (size_t)(b * S_LEN) * QKVN + 1024 + h * HD;
  const size_t vbase = (size_t)bh * 64 * S_LEN;

  for (int t0 = 0; t0 < S_LEN; t0 += 128) {
    __syncthreads();
#pragma unroll
    for (int it = 0; it < 2; ++it) {
      int idx = it * 512 + tid;
      int r = idx >> 3, dc = (idx & 7) * 8;          // K: 128 rows x 64
      *(uint4*)&lk[r][dc] = *(const uint4*)&qk[kbase + (size_t)(t0 + r) * QKVN + dc];
      int d = idx >> 4, sc = (idx & 15) * 8;          // V^T: 64 rows x 128
      *(uint4*)&lvt[d][sc] = *(const uint4*)&vt[vbase + (size_t)d * S_LEN + t0 + sc];
    }
    __syncthreads();

    f32x4 s[8];
#pragma unroll
    for (int n = 0; n < 8; ++n) s[n] = zero;
    __builtin_amdgcn_s_setprio(1);
#pragma unroll
    for (int ks = 0; ks < 2; ++ks) {
#pragma unroll
      for (int n = 0; n < 8; ++n) {
        bf16x8 bk = *(const bf16x8*)&lk[n * 16 + lo][ks * 32 + hi * 8];
        s[n] = __builtin_amdgcn_mfma_f32_16x16x32_bf16(qf[ks], bk, s[n], 0, 0, 0);
      }
    }
    __builtin_amdgcn_s_setprio(0);

#pragma unroll
    for (int j = 0; j < 4; ++j) {
      float mx = fmaxf(fmaxf(fmaxf(s[0][j], s[1][j]), fmaxf(s[2][j], s[3][j])),
                       fmaxf(fmaxf(s[4][j], s[5][j]), fmaxf(s[6][j], s[7][j])));
      mx = fmaxf(mx, __shfl_xor(mx, 1));
      mx = fmaxf(mx, __shfl_xor(mx, 2));
      mx = fmaxf(mx, __shfl_xor(mx, 4));
      mx = fmaxf(mx, __shfl_xor(mx, 8));
      if (__any(mx > mrow[j] + 8.0f)) {
        float mn = fmaxf(mrow[j], mx);
        float corr = __expf(mrow[j] - mn);
        mrow[j] = mn;
        lrow[j] *= corr;
#pragma unroll
        for (int n = 0; n < 4; ++n) oa[n][j] *= corr;
      }
      float psum = 0.f;
#pragma unroll
      for (int n = 0; n < 8; ++n) {
        float p = __expf(s[n][j] - mrow[j]);
        psum += p;
        lp[w][hi * 4 + j][n * 16 + lo] = (bf16_t)p;
      }
      lrow[j] += psum;
    }

    __builtin_amdgcn_s_setprio(1);
#pragma unroll
    for (int kk = 0; kk < 128; kk += 32) {
      bf16x8 ap = *(const bf16x8*)&lp[w][lo][kk + hi * 8];
#pragma unroll
      for (int n = 0; n < 4; ++n) {
        bf16x8 bv = *(const bf16x8*)&lvt[n * 16 + lo][kk + hi * 8];
        oa[n] = __builtin_amdgcn_mfma_f32_16x16x32_bf16(ap, bv, oa[n], 0, 0, 0);
      }
    }
    __builtin_amdgcn_s_setprio(0);
  }

#pragma unroll
  for (int j = 0; j < 4; ++j) {
    float ls = lrow[j];
    ls += __shfl_xor(ls, 1); ls += __shfl_xor(ls, 2);
    ls += __shfl_xor(ls, 4); ls += __shfl_xor(ls, 8);
    float inv = 1.0f / ls;
    int row = q0 + w * 16 + hi * 4 + j;
#pragma unroll
    for (int n = 0; n < 4; ++n)
      o[((size_t)(b * S_LEN) + row) * DM + h * HD + n * 16 + lo] = (bf16_t)(oa[n][j] * inv);
  }
}

// ---------------------------------------------------------------------------------
extern "C" void kernel_launch(void* const* d_in, const int* in_sizes, int n_in,
                              void* d_out, int out_size, void* d_ws, size_t ws_size,
                              hipStream_t stream) {
  const float* x    = (const float*)d_in[0];
  const float* te   = (const float*)d_in[1];
  const float* wn1  = (const float*)d_in[2];
  const float* t1w1 = (const float*)d_in[3];
  const float* t1b1 = (const float*)d_in[4];
  const float* t1w2 = (const float*)d_in[5];
  const float* t1b2 = (const float*)d_in[6];
  const float* wn2  = (const float*)d_in[7];
  const float* t2w1 = (const float*)d_in[8];
  const float* t2b1 = (const float*)d_in[9];
  const float* t2w2 = (const float*)d_in[10];
  const float* t2b2 = (const float*)d_in[11];
  const float* wq   = (const float*)d_in[12];
  const float* bq   = (const float*)d_in[13];
  const float* wk   = (const float*)d_in[14];
  const float* bk   = (const float*)d_in[15];
  const float* wv   = (const float*)d_in[16];
  const float* bv   = (const float*)d_in[17];
  const float* wo   = (const float*)d_in[18];
  const float* bo   = (const float*)d_in[19];
  const float* wg   = (const float*)d_in[20];
  const float* wu   = (const float*)d_in[21];
  const float* wd   = (const float*)d_in[22];
  float* out = (float*)d_out;

  char* ws = (char*)d_ws;
  const size_t MB = 1ull << 20;
  bf16_t* woT   = (bf16_t*)(ws + 0 * MB);    // 2 MB
  bf16_t* wguT  = (bf16_t*)(ws + 2 * MB);    // 16 MB (interleaved gate|up, 8192 x 1024)
  bf16_t* wdT   = (bf16_t*)(ws + 18 * MB);   // 8 MB
  bf16_t* nx    = (bf16_t*)(ws + 26 * MB);   // 8 MB
  bf16_t* wqkvT = (bf16_t*)(ws + 34 * MB);   // 6 MB
  bf16_t* qkvb  = (bf16_t*)(ws + 40 * MB);   // 24 MB (v-region unwritten)
  bf16_t* vt    = (bf16_t*)(ws + 64 * MB);   // 8 MB
  bf16_t* gb    = (bf16_t*)(ws + 40 * MB);   // 32 MB, aliases qkvb+vt (dead by FFN)
  bf16_t* attnb = (bf16_t*)(ws + 72 * MB);   // 8 MB
  bf16_t* x2b   = (bf16_t*)(ws + 80 * MB);   // 8 MB
  float*  cs    = (float*)(ws + 88 * MB);    // 1 MB
  float*  ss1   = (float*)(ws + 89 * MB);
  float*  ss2   = (float*)(ws + 89 * MB + 16384);
  float*  htmp  = (float*)(ws + 89 * MB + 32768);
  float*  bcat  = (float*)(ws + 89 * MB + 40960);

  gemv_k<<<dim3(32, 2), 256, 0, stream>>>(te, t1w1, t1b1, htmp, 1024, 1);
  gemv_k<<<dim3(64, 2), 256, 0, stream>>>(htmp, t1w2, t1b2, ss1, 2048, 0);
  gemv_k<<<dim3(32, 2), 256, 0, stream>>>(te, t2w1, t2b1, htmp, 1024, 1);
  gemv_k<<<dim3(64, 2), 256, 0, stream>>>(htmp, t2w2, t2b2, ss2, 2048, 0);

  // all weight transposes + bias concat + RoPE table in one launch
  prep_k<<<8460, 256, 0, stream>>>(wq, wk, wv, wo, wg, wu, wd,
                                   wqkvT, woT, wguT, wdT, bq, bk, bv, bcat, cs);

  ada_rms_k<float><<<MROWS, 256, 0, stream>>>(x, wn1, ss1, nx);

  // merged QKV projection, 256x128 tiles (BM=256): fused bias+RoPE (q,k), V -> vt
  gemm_bt<5, 64><<<dim3(24, 16), 512, 0, stream>>>(nx, wqkvT, MROWS, QKVN, DM,
                                                   bcat, nullptr, nullptr, qkvb, nullptr, cs, vt);

  attn_k<<<512, 512, 0, stream>>>(qkvb, vt, attnb);

  // WO + bias + residual -> x2 (grid-limited: BK=128 dbuf, half the barriers)
  gemm_bt<1, 128><<<dim3(8, 32), 256, 0, stream>>>(attnb, woT, MROWS, DM, DM,
                                                   bo, x, nullptr, x2b, nullptr, nullptr, nullptr);

  ada_rms_k<bf16_t><<<MROWS, 256, 0, stream>>>(x2b, wn2, ss2, nx);

  // fused FFN, 256x128 tiles: gb = gelu(nx@wg) * (nx@wu)  (one GEMM, N=8192 ilv)
  gemm_bt<6, 64><<<dim3(64, 16), 512, 0, stream>>>(nx, wguT, MROWS, 2 * DFF, DM,
                                                   nullptr, nullptr, nullptr, gb, nullptr, nullptr, nullptr);
  // down + residual -> out (grid-limited: BK=128 dbuf)
  gemm_bt<4, 128><<<dim3(8, 32), 256, 0, stream>>>(gb, wdT, MROWS, DM, DFF,
                                                   nullptr, nullptr, x2b, nullptr, out, nullptr, nullptr);
}

// Round 19
// 302.656 us; speedup vs baseline: 1.1700x; 1.0489x over previous
//
#include <hip/hip_runtime.h>
#include <hip/hip_bf16.h>

typedef __bf16 bf16_t;
typedef __bf16 bf16x8 __attribute__((ext_vector_type(8)));
typedef float f32x4 __attribute__((ext_vector_type(4)));

typedef __attribute__((address_space(3))) void lds_void_t;
typedef const __attribute__((address_space(1))) void gbl_void_t;

static constexpr int S_LEN = 2048;
static constexpr int NBATCH = 2;
static constexpr int DM = 1024;
static constexpr int NH = 16;
static constexpr int HD = 64;
static constexpr int DFF = 4096;
static constexpr int MROWS = NBATCH * S_LEN;   // 4096
static constexpr int QKVN = 3072;              // merged q|k|v columns

// ---------------- dual GEMV: both adaLN branches in one launch ---------------------
// blockIdx.y in [0,4): half = y>>1 selects (Wa,biasa,outa) vs (Wb,...), b = y&1.
__global__ __launch_bounds__(256) void gemv2_k(
    const float* __restrict__ vinA, const float* __restrict__ vinB,
    const float* __restrict__ Wa, const float* __restrict__ Wb,
    const float* __restrict__ ba, const float* __restrict__ bb,
    float* __restrict__ outa, float* __restrict__ outb2, int N, int dosilu) {
  int half = blockIdx.y >> 1, b = blockIdx.y & 1;
  const float* W   = half ? Wb : Wa;
  const float* bia = half ? bb : ba;
  const float* vin = half ? vinB : vinA;
  float* out       = half ? outb2 : outa;
  int tj = threadIdx.x & 31, ti = threadIdx.x >> 5;
  int j = blockIdx.x * 32 + tj;
  const float* v = vin + b * DM;
  float acc = 0.f;
  int i0 = ti * 128;
#pragma unroll 8
  for (int i = i0; i < i0 + 128; ++i) acc += v[i] * W[(size_t)i * N + j];
  __shared__ float red[8][32];
  red[ti][tj] = acc;
  __syncthreads();
  if (threadIdx.x < 32) {
    float a = 0.f;
#pragma unroll
    for (int t = 0; t < 8; ++t) a += red[t][threadIdx.x];
    a += bia[j - tj + threadIdx.x];
    if (dosilu) a = a / (1.0f + expf(-a));
    out[(size_t)b * N + blockIdx.x * 32 + threadIdx.x] = a;
  }
}

// ---------------- ada-RMSNorm: out = x*rsqrt(mean x^2+eps)*w*(1+scale)+shift -------
template<typename T>
__global__ __launch_bounds__(256) void ada_rms_k(const T* __restrict__ x,
    const float* __restrict__ wnorm, const float* __restrict__ ss,
    bf16_t* __restrict__ out) {
  int row = blockIdx.x;                // 0..4095  (b = row/2048)
  int b = row >> 11;
  const T* xr = x + (size_t)row * DM;
  float xl[4]; float s = 0.f;
#pragma unroll
  for (int i = 0; i < 4; ++i) { xl[i] = (float)xr[threadIdx.x + i * 256]; s += xl[i] * xl[i]; }
#pragma unroll
  for (int d = 1; d < 64; d <<= 1) s += __shfl_xor(s, d);
  __shared__ float red[4];
  int w = threadIdx.x >> 6;
  if ((threadIdx.x & 63) == 0) red[w] = s;
  __syncthreads();
  s = red[0] + red[1] + red[2] + red[3];
  float r = rsqrtf(s * (1.0f / DM) + 1e-5f);
  bf16_t* orow = out + (size_t)row * DM;
#pragma unroll
  for (int i = 0; i < 4; ++i) {
    int j = threadIdx.x + i * 256;
    float sc = ss[b * 2048 + j], sh = ss[b * 2048 + 1024 + j];
    orow[j] = (bf16_t)(xl[i] * r * wnorm[j] * (1.0f + sc) + sh);
  }
}

// ---------------- merged prep: transposes (64x32 tiles, uint4 stores) + bias concat
//                  + RoPE table, ONE launch ---------------------------------------
__global__ __launch_bounds__(256) void prep_k(
    const float* __restrict__ wq, const float* __restrict__ wk,
    const float* __restrict__ wv, const float* __restrict__ wo,
    const float* __restrict__ wg, const float* __restrict__ wu,
    const float* __restrict__ wd,
    bf16_t* __restrict__ wqkvT, bf16_t* __restrict__ woT,
    bf16_t* __restrict__ wguT, bf16_t* __restrict__ wdT,
    const float* __restrict__ bq, const float* __restrict__ bk,
    const float* __restrict__ bv, float* __restrict__ bcat,
    float* __restrict__ cs) {
  int id = blockIdx.x;
  if (id >= 8204) {
    int idx = (id - 8204) * 256 + threadIdx.x;    // 0..65535
    int i = idx & 31, s = idx >> 5;
    float inv = powf(10000.0f, -(float)i / 32.0f);
    float ang = (float)s * inv;
    float c = cosf(ang), sn = sinf(ang);
    cs[s * 64 + i] = c;  cs[s * 64 + i + 32] = c;
    cs[S_LEN * 64 + s * 64 + i] = sn;  cs[S_LEN * 64 + s * 64 + i + 32] = sn;
    return;
  }
  if (id >= 8192) {
    int i = (id - 8192) * 256 + threadIdx.x;
    if (i < 3072)
      bcat[i] = i < 1024 ? bq[i] : (i < 2048 ? bk[i - 1024] : bv[i - 2048]);
    return;
  }
  const float* in; bf16_t* outp; int K, N, ilv, t;
  if (id < 2048) {
    int j = id >> 9; t = id & 511; K = 1024; N = 1024; ilv = 0;
    in   = j == 0 ? wq : j == 1 ? wk : j == 2 ? wv : wo;
    outp = j == 3 ? woT : wqkvT + (size_t)j * 1024 * 1024;
  } else if (id < 6144) {
    int j = (id - 2048) >> 11; t = (id - 2048) & 2047; K = 1024; N = 4096;
    ilv = 1 + j; in = j ? wu : wg; outp = wguT;
  } else {
    t = id - 6144; K = 4096; N = 1024; ilv = 0; in = wd; outp = wdT;
  }
  int nbx = N >> 5;
  int n0 = (t % nbx) * 32, k0 = (t / nbx) * 64;
  __shared__ float tl[64][33];
  int tx = threadIdx.x & 31, ty = threadIdx.x >> 5;
#pragma unroll
  for (int i = 0; i < 64; i += 8)
    tl[ty + i][tx] = in[(size_t)(k0 + ty + i) * N + n0 + tx];
  __syncthreads();
  {
    int jn = threadIdx.x >> 3, kc = (threadIdx.x & 7) * 8;
    int n = n0 + jn;
    int row = (ilv == 0) ? n : ((n >> 4) * 32 + (n & 15) + (ilv == 2 ? 16 : 0));
    __align__(16) bf16_t v[8];
#pragma unroll
    for (int j = 0; j < 8; ++j) v[j] = (bf16_t)tl[kc + j][jn];
    *(uint4*)&outp[(size_t)row * K + k0 + kc] = *(uint4*)v;
  }
}

// ---------------- bf16 MFMA GEMM: C = A[M][K] @ BT[N][K]^T -------------------------
// BK=64: BM=256 x BN=128 tile, 8 waves (512 thr), SINGLE-buffered 48KB LDS,
//   launch_bounds(512,4) (the (512,6) VGPR cap of 85 spilled accumulators: R14).
// BK=128: BM=128 dbuf (128KB) for grid-limited GEMMs (1 block/CU), proven R10.
// Loop-carried stage pointers; both-sides chunk swizzle -> 0 bank conflicts (R9).
// EPI: 1 = +bias +residf(f32) -> bf16 out (WO + residual -> x2)
//      4 = +residb(bf16) -> f32 out       (down + residual -> d_out)
//      5 = QKV fused: +bias, q/k RoPE, q scaled 1/8; V -> vt[bh][d][s]
//      6 = fused FFN gate*up: interleaved BT; out = gelu(g)*u -> gb[4096][4096]
template<int EPI, int BK>
__global__ __launch_bounds__((BK == 64) ? 512 : 256, (BK == 64) ? 4 : 1) void gemm_bt(
    const bf16_t* __restrict__ A, const bf16_t* __restrict__ BT,
    int M, int N, int K,
    const float* __restrict__ bias, const float* __restrict__ residf,
    const bf16_t* __restrict__ residb, bf16_t* outb, float* outf,
    const float* __restrict__ cstab, bf16_t* __restrict__ vt) {
  constexpr int DB = (BK == 64) ? 1 : 2;
  constexpr int BM = (BK == 64) ? 256 : 128;
  const int col0 = blockIdx.x * 128, row0 = blockIdx.y * BM;
  const int tid = threadIdx.x, l = tid & 63, w = tid >> 6;   // w: 0..7 (BK64) / 0..3
  const int wr = (w >> 1) * 64, wc = (w & 1) * 64;
  const int lo = l & 15, hi = l >> 4;
  __shared__ __align__(16) bf16_t lA[DB][BM][BK];
  __shared__ __align__(16) bf16_t lB[DB][128][BK];
  f32x4 zero = {0.f, 0.f, 0.f, 0.f};
  f32x4 acc[4][4];
#pragma unroll
  for (int m = 0; m < 4; ++m)
#pragma unroll
    for (int n = 0; n < 4; ++n) acc[m][n] = zero;

  const int cmask = (BK == 64) ? (lo & 7) : lo;       // read-side swizzle key
  const int NT = K / BK;

  auto compute = [&](int buf) {
#pragma unroll
    for (int kk = 0; kk < BK; kk += 32) {
      bf16x8 af[4], bfr[4];
#pragma unroll
      for (int m = 0; m < 4; ++m)
        af[m] = *(const bf16x8*)&lA[buf][wr + m * 16 + lo][(((kk >> 3) + hi) ^ cmask) * 8];
#pragma unroll
      for (int n = 0; n < 4; ++n)
        bfr[n] = *(const bf16x8*)&lB[buf][wc + n * 16 + lo][(((kk >> 3) + hi) ^ cmask) * 8];
#pragma unroll
      for (int m = 0; m < 4; ++m)
#pragma unroll
        for (int n = 0; n < 4; ++n)
          acc[m][n] = __builtin_amdgcn_mfma_f32_16x16x32_bf16(af[m], bfr[n], acc[m][n], 0, 0, 0);
    }
  };

  if constexpr (DB == 1) {
    // BM=256: A = 4 issues/wave (rows w*32+i*8), B = 2 issues/wave (rows w*16+i*8)
    const int lrow = l >> 3;
    const int swzb = ((l & 7) ^ lrow) * 16;
    const char* pA[4]; const char* pB[2];
#pragma unroll
    for (int i = 0; i < 4; ++i)
      pA[i] = (const char*)&A[(size_t)(row0 + w * 32 + i * 8 + lrow) * K] + swzb;
#pragma unroll
    for (int i = 0; i < 2; ++i)
      pB[i] = (const char*)&BT[(size_t)(col0 + w * 16 + i * 8 + lrow) * K] + swzb;
    for (int t = 0; t < NT; ++t) {
      __syncthreads();               // prior compute done reading LDS
#pragma unroll
      for (int i = 0; i < 4; ++i) {
        __builtin_amdgcn_global_load_lds((gbl_void_t*)pA[i],
            (lds_void_t*)&lA[0][w * 32 + i * 8][0], 16, 0, 0);
        pA[i] += 128;                // BK=64 bf16 = 128 B
      }
#pragma unroll
      for (int i = 0; i < 2; ++i) {
        __builtin_amdgcn_global_load_lds((gbl_void_t*)pB[i],
            (lds_void_t*)&lB[0][w * 16 + i * 8][0], 16, 0, 0);
        pB[i] += 128;
      }
      __syncthreads();               // vmcnt(0) drain: tile landed
      compute(0);
    }
  } else {
    const int lrow = l >> 4;                        // 4 rows x 16 chunks per issue
    const char* pA[8]; const char* pB[8];
#pragma unroll
    for (int i = 0; i < 8; ++i) {
      int rbase = w * 32 + i * 4;
      int key = (i * 4 + lrow) & 15;
      int swzb = ((l & 15) ^ key) * 16;
      pA[i] = (const char*)&A[(size_t)(row0 + rbase + lrow) * K] + swzb;
      pB[i] = (const char*)&BT[(size_t)(col0 + rbase + lrow) * K] + swzb;
    }
    auto stage_p = [&](int buf) {
#pragma unroll
      for (int i = 0; i < 8; ++i) {
        int rbase = w * 32 + i * 4;
        __builtin_amdgcn_global_load_lds((gbl_void_t*)pA[i], (lds_void_t*)&lA[buf][rbase][0], 16, 0, 0);
        __builtin_amdgcn_global_load_lds((gbl_void_t*)pB[i], (lds_void_t*)&lB[buf][rbase][0], 16, 0, 0);
        pA[i] += 256; pB[i] += 256;  // BK=128 bf16 = 256 B
      }
    };
    stage_p(0);
    __syncthreads();                 // drains vmcnt(0): tile 0 landed
    int cur = 0;
    for (int t = 0; t < NT; ++t) {
      if (t + 1 < NT) stage_p(cur ^ 1);   // issue next BEFORE compute
      compute(cur);
      __syncthreads();
      cur ^= 1;
    }
  }

  if (EPI == 5) {
    if (col0 >= 2048) {
#pragma unroll
      for (int m = 0; m < 4; ++m) {
#pragma unroll
        for (int n = 0; n < 4; ++n) {
          int cl = col0 + wc + n * 16 + lo;
          int r0 = row0 + wr + m * 16 + hi * 4;      // j=0 row
          int dfull = cl - 2048;
          int bh = (r0 >> 11) * 16 + (dfull >> 6);
          int d = dfull & 63;
          float bb = bias[cl];
          __align__(8) bf16_t tmp[4];
#pragma unroll
          for (int j = 0; j < 4; ++j) tmp[j] = (bf16_t)(acc[m][n][j] + bb);
          *(uint2*)&vt[((size_t)bh * 64 + d) * S_LEN + (r0 & 2047)] = *(uint2*)tmp;
        }
      }
    } else {
#pragma unroll
      for (int m = 0; m < 4; ++m) {
#pragma unroll
        for (int n = 0; n < 2; ++n) {
          int cl = col0 + wc + n * 16 + lo;          // i = cl&63 < 32
          int i = cl & 63;
          float b1 = bias[cl], b2 = bias[cl + 32];
          float scale = (cl < 1024) ? 0.125f : 1.0f;
#pragma unroll
          for (int j = 0; j < 4; ++j) {
            int r = row0 + wr + m * 16 + hi * 4 + j;
            int s = r & 2047;
            float c = cstab[s * 64 + i], sn = cstab[S_LEN * 64 + s * 64 + i];
            float x1 = acc[m][n][j] + b1, x2 = acc[m][n + 2][j] + b2;
            size_t idx = (size_t)r * N + cl;
            outb[idx]      = (bf16_t)((x1 * c - x2 * sn) * scale);
            outb[idx + 32] = (bf16_t)((x2 * c + x1 * sn) * scale);
          }
        }
      }
    }
    return;
  }

  if (EPI == 6) {
    // even n = gate col j, odd n = up col j, j = (cl>>5)*16 + lo (same lane pair)
#pragma unroll
    for (int m = 0; m < 4; ++m) {
#pragma unroll
      for (int p = 0; p < 2; ++p) {
        int clg = col0 + wc + 2 * p * 16;
        int jcol = ((clg >> 5) << 4) + lo;
#pragma unroll
        for (int j = 0; j < 4; ++j) {
          int r = row0 + wr + m * 16 + hi * 4 + j;
          float g = acc[m][2 * p][j];
          float u = acc[m][2 * p + 1][j];
          g = 0.5f * g * (1.0f + erff(g * 0.70710678118f));
          outb[(size_t)r * DFF + jcol] = (bf16_t)(g * u);
        }
      }
    }
    return;
  }

#pragma unroll
  for (int m = 0; m < 4; ++m) {
#pragma unroll
    for (int n = 0; n < 4; ++n) {
#pragma unroll
      for (int j = 0; j < 4; ++j) {
        int r = row0 + wr + m * 16 + hi * 4 + j;      // C/D: row=(l>>4)*4+reg
        int cl = col0 + wc + n * 16 + lo;             //      col=l&15   (m89-verified)
        size_t idx = (size_t)r * N + cl;
        float vv = acc[m][n][j];
        if (EPI == 1)      { vv += bias[cl] + residf[idx]; outb[idx] = (bf16_t)vv; }
        else               { vv += (float)residb[idx]; outf[idx] = vv; }
      }
    }
  }
}

// ---------------- flash attention: 8 waves x 16 q-rows, KV tile = 128 --------------
// R7/R15-proven structure (87.5us); lp stride 132 (R18).
__global__ __launch_bounds__(512, 4) void attn_k(const bf16_t* __restrict__ qk,
    const bf16_t* __restrict__ vt, bf16_t* __restrict__ o) {
  int g = blockIdx.x;
  int orig = (g & 7) * 64 + (g >> 3);    // XCD swizzle: 64 consecutive per XCD
  int qblk = orig & 15;
  int bh = orig >> 4;
  int b = bh >> 4, h = bh & 15;
  const int q0 = qblk * 128;
  const int tid = threadIdx.x, l = tid & 63, w = tid >> 6;   // w in 0..7
  const int lo = l & 15, hi = l >> 4;

  __shared__ __align__(16) bf16_t lk[128][72];
  __shared__ __align__(16) bf16_t lvt[64][136];   // [d][kv]
  __shared__ __align__(16) bf16_t lp[8][16][132]; // per-wave P (16 rows x 128 kv)

  bf16x8 qf[2];
#pragma unroll
  for (int ks = 0; ks < 2; ++ks)
    qf[ks] = *(const bf16x8*)&qk[((size_t)(b * S_LEN) + q0 + w * 16 + lo) * QKVN
                                 + h * HD + ks * 32 + hi * 8];

  f32x4 zero = {0.f, 0.f, 0.f, 0.f};
  f32x4 oa[4];
#pragma unroll
  for (int n = 0; n < 4; ++n) oa[n] = zero;
  float mrow[4], lrow[4];
#pragma unroll
  for (int j = 0; j < 4; ++j) { mrow[j] = -1e30f; lrow[j] = 0.f; }

  const size_t kbase = (size_t)(b * S_LEN) * QKVN + 1024 + h * HD;
  const size_t vbase = (size_t)bh * 64 * S_LEN;

  for (int t0 = 0; t0 < S_LEN; t0 += 128) {
    __syncthreads();
#pragma unroll
    for (int it = 0; it < 2; ++it) {
      int idx = it * 512 + tid;
      int r = idx >> 3, dc = (idx & 7) * 8;          // K: 128 rows x 64
      *(uint4*)&lk[r][dc] = *(const uint4*)&qk[kbase + (size_t)(t0 + r) * QKVN + dc];
      int d = idx >> 4, sc = (idx & 15) * 8;          // V^T: 64 rows x 128
      *(uint4*)&lvt[d][sc] = *(const uint4*)&vt[vbase + (size_t)d * S_LEN + t0 + sc];
    }
    __syncthreads();

    f32x4 s[8];
#pragma unroll
    for (int n = 0; n < 8; ++n) s[n] = zero;
    __builtin_amdgcn_s_setprio(1);
#pragma unroll
    for (int ks = 0; ks < 2; ++ks) {
#pragma unroll
      for (int n = 0; n < 8; ++n) {
        bf16x8 bk = *(const bf16x8*)&lk[n * 16 + lo][ks * 32 + hi * 8];
        s[n] = __builtin_amdgcn_mfma_f32_16x16x32_bf16(qf[ks], bk, s[n], 0, 0, 0);
      }
    }
    __builtin_amdgcn_s_setprio(0);

#pragma unroll
    for (int j = 0; j < 4; ++j) {
      float mx = fmaxf(fmaxf(fmaxf(s[0][j], s[1][j]), fmaxf(s[2][j], s[3][j])),
                       fmaxf(fmaxf(s[4][j], s[5][j]), fmaxf(s[6][j], s[7][j])));
      mx = fmaxf(mx, __shfl_xor(mx, 1));
      mx = fmaxf(mx, __shfl_xor(mx, 2));
      mx = fmaxf(mx, __shfl_xor(mx, 4));
      mx = fmaxf(mx, __shfl_xor(mx, 8));
      if (__any(mx > mrow[j] + 8.0f)) {
        float mn = fmaxf(mrow[j], mx);
        float corr = __expf(mrow[j] - mn);
        mrow[j] = mn;
        lrow[j] *= corr;
#pragma unroll
        for (int n = 0; n < 4; ++n) oa[n][j] *= corr;
      }
      float psum = 0.f;
#pragma unroll
      for (int n = 0; n < 8; ++n) {
        float p = __expf(s[n][j] - mrow[j]);
        psum += p;
        lp[w][hi * 4 + j][n * 16 + lo] = (bf16_t)p;
      }
      lrow[j] += psum;
    }

    __builtin_amdgcn_s_setprio(1);
#pragma unroll
    for (int kk = 0; kk < 128; kk += 32) {
      bf16x8 ap = *(const bf16x8*)&lp[w][lo][kk + hi * 8];
#pragma unroll
      for (int n = 0; n < 4; ++n) {
        bf16x8 bv = *(const bf16x8*)&lvt[n * 16 + lo][kk + hi * 8];
        oa[n] = __builtin_amdgcn_mfma_f32_16x16x32_bf16(ap, bv, oa[n], 0, 0, 0);
      }
    }
    __builtin_amdgcn_s_setprio(0);
  }

#pragma unroll
  for (int j = 0; j < 4; ++j) {
    float ls = lrow[j];
    ls += __shfl_xor(ls, 1); ls += __shfl_xor(ls, 2);
    ls += __shfl_xor(ls, 4); ls += __shfl_xor(ls, 8);
    float inv = 1.0f / ls;
    int row = q0 + w * 16 + hi * 4 + j;
#pragma unroll
    for (int n = 0; n < 4; ++n)
      o[((size_t)(b * S_LEN) + row) * DM + h * HD + n * 16 + lo] = (bf16_t)(oa[n][j] * inv);
  }
}

// ---------------------------------------------------------------------------------
extern "C" void kernel_launch(void* const* d_in, const int* in_sizes, int n_in,
                              void* d_out, int out_size, void* d_ws, size_t ws_size,
                              hipStream_t stream) {
  const float* x    = (const float*)d_in[0];
  const float* te   = (const float*)d_in[1];
  const float* wn1  = (const float*)d_in[2];
  const float* t1w1 = (const float*)d_in[3];
  const float* t1b1 = (const float*)d_in[4];
  const float* t1w2 = (const float*)d_in[5];
  const float* t1b2 = (const float*)d_in[6];
  const float* wn2  = (const float*)d_in[7];
  const float* t2w1 = (const float*)d_in[8];
  const float* t2b1 = (const float*)d_in[9];
  const float* t2w2 = (const float*)d_in[10];
  const float* t2b2 = (const float*)d_in[11];
  const float* wq   = (const float*)d_in[12];
  const float* bq   = (const float*)d_in[13];
  const float* wk   = (const float*)d_in[14];
  const float* bk   = (const float*)d_in[15];
  const float* wv   = (const float*)d_in[16];
  const float* bv   = (const float*)d_in[17];
  const float* wo   = (const float*)d_in[18];
  const float* bo   = (const float*)d_in[19];
  const float* wg   = (const float*)d_in[20];
  const float* wu   = (const float*)d_in[21];
  const float* wd   = (const float*)d_in[22];
  float* out = (float*)d_out;

  char* ws = (char*)d_ws;
  const size_t MB = 1ull << 20;
  bf16_t* woT   = (bf16_t*)(ws + 0 * MB);    // 2 MB
  bf16_t* wguT  = (bf16_t*)(ws + 2 * MB);    // 16 MB (interleaved gate|up, 8192 x 1024)
  bf16_t* wdT   = (bf16_t*)(ws + 18 * MB);   // 8 MB
  bf16_t* nx    = (bf16_t*)(ws + 26 * MB);   // 8 MB
  bf16_t* wqkvT = (bf16_t*)(ws + 34 * MB);   // 6 MB
  bf16_t* qkvb  = (bf16_t*)(ws + 40 * MB);   // 24 MB (v-region unwritten)
  bf16_t* vt    = (bf16_t*)(ws + 64 * MB);   // 8 MB
  bf16_t* gb    = (bf16_t*)(ws + 40 * MB);   // 32 MB, aliases qkvb+vt (dead by FFN)
  bf16_t* attnb = (bf16_t*)(ws + 72 * MB);   // 8 MB
  bf16_t* x2b   = (bf16_t*)(ws + 80 * MB);   // 8 MB
  float*  cs    = (float*)(ws + 88 * MB);    // 1 MB
  float*  ss1   = (float*)(ws + 89 * MB);
  float*  ss2   = (float*)(ws + 89 * MB + 16384);
  float*  htmp1 = (float*)(ws + 89 * MB + 32768);
  float*  htmp2 = (float*)(ws + 89 * MB + 40960);
  float*  bcat  = (float*)(ws + 89 * MB + 49152);

  // both adaLN time-MLPs, 2 launches total (was 4)
  gemv2_k<<<dim3(32, 4), 256, 0, stream>>>(te, te, t1w1, t2w1, t1b1, t2b1,
                                           htmp1, htmp2, 1024, 1);
  gemv2_k<<<dim3(64, 4), 256, 0, stream>>>(htmp1, htmp2, t1w2, t2w2, t1b2, t2b2,
                                           ss1, ss2, 2048, 0);

  // all weight transposes + bias concat + RoPE table in one launch
  prep_k<<<8460, 256, 0, stream>>>(wq, wk, wv, wo, wg, wu, wd,
                                   wqkvT, woT, wguT, wdT, bq, bk, bv, bcat, cs);

  ada_rms_k<float><<<MROWS, 256, 0, stream>>>(x, wn1, ss1, nx);

  // merged QKV projection, 256x128 tiles (BM=256): fused bias+RoPE (q,k), V -> vt
  gemm_bt<5, 64><<<dim3(24, 16), 512, 0, stream>>>(nx, wqkvT, MROWS, QKVN, DM,
                                                   bcat, nullptr, nullptr, qkvb, nullptr, cs, vt);

  attn_k<<<512, 512, 0, stream>>>(qkvb, vt, attnb);

  // WO + bias + residual -> x2 (grid-limited: BK=128 dbuf, half the barriers)
  gemm_bt<1, 128><<<dim3(8, 32), 256, 0, stream>>>(attnb, woT, MROWS, DM, DM,
                                                   bo, x, nullptr, x2b, nullptr, nullptr, nullptr);

  ada_rms_k<bf16_t><<<MROWS, 256, 0, stream>>>(x2b, wn2, ss2, nx);

  // fused FFN, 256x128 tiles: gb = gelu(nx@wg) * (nx@wu)  (one GEMM, N=8192 ilv)
  gemm_bt<6, 64><<<dim3(64, 16), 512, 0, stream>>>(nx, wguT, MROWS, 2 * DFF, DM,
                                                   nullptr, nullptr, nullptr, gb, nullptr, nullptr, nullptr);
  // down + residual -> out (grid-limited: BK=128 dbuf)
  gemm_bt<4, 128><<<dim3(8, 32), 256, 0, stream>>>(gb, wdT, MROWS, DM, DFF,
                                                   nullptr, nullptr, x2b, nullptr, out, nullptr, nullptr);
}